// Round 4
// baseline (1250.327 us; speedup 1.0000x reference)
//
#include <hip/hip_runtime.h>
#include <hip/hip_bf16.h>
#include <math.h>

#define BQ 32
#define SQ 256
#define MTOK 8192       // B*S
#define DD 128
#define II 256
#define NNs 16
#define RRs 8
#define KKs 4
#define LLs 4
#define ZZs 128
#define FUTs 20

typedef __attribute__((ext_vector_type(8))) short bf8v;   // 8 bf16 (4 VGPRs)
typedef __attribute__((ext_vector_type(4))) float f4v;    // 4 fp32 acc

__device__ __forceinline__ float geluf(float x){ return 0.5f*x*(1.0f+erff(x*0.70710678118654752f)); }
__device__ __forceinline__ float siluf(float x){ return x/(1.0f+__expf(-x)); }
__device__ __forceinline__ float softplusf(float x){ return fmaxf(x,0.0f)+log1pf(__expf(-fabsf(x))); }
__device__ __forceinline__ unsigned short f2bf(float x){
    __hip_bfloat16 h = __float2bfloat16(x);
    return *reinterpret_cast<unsigned short*>(&h);
}

// async global -> LDS, 16B per lane. LDS dest is wave-uniform base + lane*16.
__device__ __forceinline__ void gload_lds16(const void* g, void* l){
    __builtin_amdgcn_global_load_lds(
        (const __attribute__((address_space(1))) void*)g,
        (__attribute__((address_space(3))) void*)l, 16, 0, 0);
}

// counted-vmcnt wait + workgroup barrier (T4: never drain to 0 mid-loop).
#define PIPE_WAIT_BAR(N) do {                                   \
    __builtin_amdgcn_sched_barrier(0);                          \
    asm volatile("s_waitcnt vmcnt(" #N ")" ::: "memory");       \
    __builtin_amdgcn_s_barrier();                               \
    __builtin_amdgcn_sched_barrier(0);                          \
} while(0)

#define PIPE_END_BAR() do {                                     \
    __builtin_amdgcn_sched_barrier(0);                          \
    asm volatile("s_waitcnt lgkmcnt(0)" ::: "memory");          \
    __builtin_amdgcn_s_barrier();                               \
    __builtin_amdgcn_sched_barrier(0);                          \
} while(0)

// ---------------------------------------------------------------------------
// m97-geometry bf16 GEMM for N-wide outputs: BM=BN=128, BK=64, 256 threads,
// 4 waves each owning a 64x64 sub-tile (acc[4][4] -> 0.5 ds_read per MFMA,
// vs 0.75 at BN=64). 3-buffer LDS ring (96KB), counted-vmcnt pipeline
// (8 loads/stage/wave -> waits 16/8/0), XOR bank-swizzle (R2, conflicts=0).
// Per-CU-per-K-step staging drops 48->32KB and ds_read 96->64 instrs vs the
// BN=64 kernel; total GEMM1 VMEM demand 1.61->1.07GB (R3 was traffic-bound:
// deep pipeline was neutral, nothing latency-shaped improved).
// Requires Kd%64==0, Kd>=128, N%128==0. Grid (M/128, N/128).
// ---------------------------------------------------------------------------
template<int ACT,int ADD,int OUTBF>
__launch_bounds__(256,1)
__global__ void gemm_lds128_kernel(const unsigned short* __restrict__ A,
                                   const unsigned short* __restrict__ Bt,
                                   const float* __restrict__ bias,
                                   void* __restrict__ Cv,
                                   int M, int N, int Kd, int ldc)
{
    __shared__ __align__(16) unsigned short As[3][128*64];
    __shared__ __align__(16) unsigned short Bs[3][128*64];
    const int tid = threadIdx.x;
    const int w = tid >> 6, lane = tid & 63;
    const int ml = lane & 15, quad = lane >> 4;
    const int wm = w >> 1, wn = w & 1;            // wave -> 2x2 sub-tile grid
    const int rowBase = blockIdx.x * 128, colBase = blockIdx.y * 128;

    const int srow = w*8 + (lane>>3);             // staging row in 32-row group
    const int scol = (((lane&7) ^ (lane>>3)))*8;  // PRE-SWIZZLED global col

    f4v acc[4][4];
    #pragma unroll
    for (int i=0;i<4;i++)
      #pragma unroll
      for (int j=0;j<4;j++) acc[i][j] = (f4v){0.f,0.f,0.f,0.f};

    auto stage = [&](int buf, int kt){
        #pragma unroll
        for (int e=0;e<4;e++){
            const unsigned short* src = A + (size_t)(rowBase + srow + e*32)*Kd + kt + scol;
            gload_lds16(src, (unsigned short*)As[buf] + (w + e*4)*512);
        }
        #pragma unroll
        for (int e=0;e<4;e++){
            const unsigned short* src = Bt + (size_t)(colBase + srow + e*32)*Kd + kt + scol;
            gload_lds16(src, (unsigned short*)Bs[buf] + (w + e*4)*512);
        }
    };

    const int swz = (ml&7)*8;                     // read-side XOR (elems)

    auto compute = [&](int buf){
        #pragma unroll
        for (int ks=0; ks<2; ks++){
            const int co = (ks*32 + quad*8) ^ swz;
            bf8v a[4], b[4];
            #pragma unroll
            for (int mf=0; mf<4; mf++)
                a[mf] = *reinterpret_cast<const bf8v*>(&As[buf][(wm*64 + mf*16 + ml)*64 + co]);
            #pragma unroll
            for (int nf=0; nf<4; nf++)
                b[nf] = *reinterpret_cast<const bf8v*>(&Bs[buf][(wn*64 + nf*16 + ml)*64 + co]);
            #pragma unroll
            for (int mf=0; mf<4; mf++)
                #pragma unroll
                for (int nf=0; nf<4; nf++)
                    acc[mf][nf] = __builtin_amdgcn_mfma_f32_16x16x32_bf16(a[mf], b[nf], acc[mf][nf], 0,0,0);
        }
    };

    const int nIter = Kd >> 6;                    // >= 2 at every call site
    stage(0, 0);
    stage(1, 64);                                 // 16 loads/wave in flight

    int i = 0;
    for (; i + 2 < nIter; ++i){
        stage((i+2)%3, (i+2)<<6);                 // 24 in flight
        PIPE_WAIT_BAR(16);                        // tile i landed; 16 stay
        compute(i%3);
        PIPE_END_BAR();                           // reads done before reuse
    }
    // i == nIter-2
    PIPE_WAIT_BAR(8);                             // tile nIter-2 landed
    compute(i%3);
    PIPE_END_BAR();
    ++i;
    PIPE_WAIT_BAR(0);                             // tile nIter-1 landed
    compute(i%3);

    #pragma unroll
    for (int mf=0; mf<4; mf++){
        #pragma unroll
        for (int nf=0; nf<4; nf++){
            int col = colBase + wn*64 + nf*16 + ml;
            float bb = bias ? bias[col] : 0.0f;
            #pragma unroll
            for (int r=0;r<4;r++){
                int row = rowBase + wm*64 + mf*16 + quad*4 + r;
                float v = acc[mf][nf][r] + bb;
                if (ACT==1) v = geluf(v);
                if constexpr (OUTBF==1){
                    ((unsigned short*)Cv)[(size_t)row*ldc + col] = f2bf(v);
                } else {
                    float* cp = (float*)Cv + (size_t)row*ldc + col;
                    if (ADD) v += *cp;
                    *cp = v;
                }
            }
        }
    }
}

// ---------------------------------------------------------------------------
// BN=64 bf16 GEMM, depth-2 counted-vmcnt pipeline + XOR swizzle (R3).
// Kept for N=128 outputs (BN=128 would leave 3/4 of CUs idle).
// ---------------------------------------------------------------------------
template<int ACT,int ADD,int OUTBF>
__launch_bounds__(256,2)
__global__ void gemm_lds_kernel(const unsigned short* __restrict__ A,
                                const unsigned short* __restrict__ Bt,
                                const float* __restrict__ bias,
                                void* __restrict__ Cv,
                                int M, int N, int Kd, int ldc)
{
    __shared__ __align__(16) unsigned short As[3][128*64];
    __shared__ __align__(16) unsigned short Bs[3][64*64];
    const int tid = threadIdx.x;
    const int w = tid >> 6, lane = tid & 63;
    const int ml = lane & 15, quad = lane >> 4;
    const int rowBase = blockIdx.x * 128, colBase = blockIdx.y * 64;

    const int srow = w*8 + (lane>>3);
    const int scol = (((lane&7) ^ (lane>>3)))*8;

    f4v acc[2][4];
    #pragma unroll
    for (int i=0;i<2;i++)
      #pragma unroll
      for (int j=0;j<4;j++) acc[i][j] = (f4v){0.f,0.f,0.f,0.f};

    auto stage = [&](int buf, int kt){
        #pragma unroll
        for (int e=0;e<4;e++){
            const unsigned short* src = A + (size_t)(rowBase + srow + e*32)*Kd + kt + scol;
            gload_lds16(src, (unsigned short*)As[buf] + (w + e*4)*512);
        }
        #pragma unroll
        for (int e=0;e<2;e++){
            const unsigned short* src = Bt + (size_t)(colBase + srow + e*32)*Kd + kt + scol;
            gload_lds16(src, (unsigned short*)Bs[buf] + (w + e*4)*512);
        }
    };

    const int swz = (ml&7)*8;

    auto compute = [&](int buf){
        #pragma unroll
        for (int ks=0; ks<2; ks++){
            const int co = (ks*32 + quad*8) ^ swz;
            bf8v a0 = *reinterpret_cast<const bf8v*>(&As[buf][(w*32 +      ml)*64 + co]);
            bf8v a1 = *reinterpret_cast<const bf8v*>(&As[buf][(w*32 + 16 + ml)*64 + co]);
            #pragma unroll
            for (int nt=0; nt<4; nt++){
                bf8v b = *reinterpret_cast<const bf8v*>(&Bs[buf][(nt*16+ml)*64 + co]);
                acc[0][nt] = __builtin_amdgcn_mfma_f32_16x16x32_bf16(a0, b, acc[0][nt], 0,0,0);
                acc[1][nt] = __builtin_amdgcn_mfma_f32_16x16x32_bf16(a1, b, acc[1][nt], 0,0,0);
            }
        }
    };

    const int nIter = Kd >> 6;
    stage(0, 0);
    stage(1, 64);

    int i = 0;
    for (; i + 2 < nIter; ++i){
        stage((i+2)%3, (i+2)<<6);
        PIPE_WAIT_BAR(12);
        compute(i%3);
        PIPE_END_BAR();
    }
    PIPE_WAIT_BAR(6);
    compute(i%3);
    PIPE_END_BAR();
    ++i;
    PIPE_WAIT_BAR(0);
    compute(i%3);

    #pragma unroll
    for (int mt=0; mt<2; mt++){
        #pragma unroll
        for (int nt=0; nt<4; nt++){
            int col = colBase + nt*16 + ml;
            float bb = bias ? bias[col] : 0.0f;
            #pragma unroll
            for (int r=0;r<4;r++){
                int row = rowBase + w*32 + mt*16 + quad*4 + r;
                float v = acc[mt][nt][r] + bb;
                if (ACT==1) v = geluf(v);
                if constexpr (OUTBF==1){
                    ((unsigned short*)Cv)[(size_t)row*ldc + col] = f2bf(v);
                } else {
                    float* cp = (float*)Cv + (size_t)row*ldc + col;
                    if (ADD) v += *cp;
                    *cp = v;
                }
            }
        }
    }
}

// ---------------------------------------------------------------------------
// Legacy reg-staged GEMM (fp32 or bf16 A). Kept for GEMM3 (fp32 x_ego, K=64)
// and as the GEMM1 fallback when ws_size can't hold the bf16 x_cam cast.
// ---------------------------------------------------------------------------
template<int ACT,int ADD,int OUTBF,typename AT>
__launch_bounds__(256,2)
__global__ void gemm_bf16_kernel(const AT* __restrict__ A,
                                 const unsigned short* __restrict__ Bt,
                                 const float* __restrict__ bias,
                                 void* __restrict__ Cv,
                                 int M, int N, int Kd, int ldc)
{
    constexpr int LDK = 72;
    __shared__ unsigned short As[128*LDK];
    __shared__ unsigned short Bs[64*LDK];
    const int tid = threadIdx.x;
    const int w = tid >> 6, lane = tid & 63;
    const int ml = lane & 15, quad = lane >> 4;
    const int rowBase = blockIdx.x * 128, colBase = blockIdx.y * 64;

    f4v acc[2][4];
    #pragma unroll
    for (int i=0;i<2;i++)
      #pragma unroll
      for (int j=0;j<4;j++) acc[i][j] = (f4v){0.f,0.f,0.f,0.f};

    bf8v pa[4], pb[2];
    const int ar = tid >> 3, as8 = (tid & 7) * 8;

    auto loadTile = [&](int kt){
        #pragma unroll
        for (int e=0;e<4;e++){
            int r = ar + e*32;
            if constexpr (sizeof(AT)==2){
                pa[e] = *reinterpret_cast<const bf8v*>(
                    (const unsigned short*)A + (size_t)(rowBase+r)*Kd + kt + as8);
            } else {
                const float* ap = (const float*)A + (size_t)(rowBase+r)*Kd + kt + as8;
                float4 v0 = *reinterpret_cast<const float4*>(ap);
                float4 v1 = *reinterpret_cast<const float4*>(ap+4);
                union { unsigned short u[8]; bf8v v; } o;
                o.u[0]=f2bf(v0.x); o.u[1]=f2bf(v0.y); o.u[2]=f2bf(v0.z); o.u[3]=f2bf(v0.w);
                o.u[4]=f2bf(v1.x); o.u[5]=f2bf(v1.y); o.u[6]=f2bf(v1.z); o.u[7]=f2bf(v1.w);
                pa[e] = o.v;
            }
        }
        #pragma unroll
        for (int e=0;e<2;e++){
            int r = ar + e*32;
            pb[e] = *reinterpret_cast<const bf8v*>(
                Bt + (size_t)(colBase+r)*Kd + kt + as8);
        }
    };

    loadTile(0);

    for (int kt=0; kt<Kd; kt+=64){
        #pragma unroll
        for (int e=0;e<4;e++) *reinterpret_cast<bf8v*>(&As[(ar+e*32)*LDK + as8]) = pa[e];
        #pragma unroll
        for (int e=0;e<2;e++) *reinterpret_cast<bf8v*>(&Bs[(ar+e*32)*LDK + as8]) = pb[e];
        __syncthreads();
        if (kt + 64 < Kd) loadTile(kt + 64);
        #pragma unroll
        for (int ks=0; ks<2; ks++){
            bf8v a0 = *reinterpret_cast<bf8v*>(&As[(w*32 +      ml)*LDK + ks*32 + quad*8]);
            bf8v a1 = *reinterpret_cast<bf8v*>(&As[(w*32 + 16 + ml)*LDK + ks*32 + quad*8]);
            #pragma unroll
            for (int nt=0; nt<4; nt++){
                bf8v b = *reinterpret_cast<bf8v*>(&Bs[(nt*16+ml)*LDK + ks*32 + quad*8]);
                acc[0][nt] = __builtin_amdgcn_mfma_f32_16x16x32_bf16(a0, b, acc[0][nt], 0,0,0);
                acc[1][nt] = __builtin_amdgcn_mfma_f32_16x16x32_bf16(a1, b, acc[1][nt], 0,0,0);
            }
        }
        __syncthreads();
    }

    #pragma unroll
    for (int mt=0; mt<2; mt++){
        #pragma unroll
        for (int nt=0; nt<4; nt++){
            int col = colBase + nt*16 + ml;
            float bb = bias ? bias[col] : 0.0f;
            #pragma unroll
            for (int r=0;r<4;r++){
                int row = rowBase + w*32 + mt*16 + quad*4 + r;
                float v = acc[mt][nt][r] + bb;
                if (ACT==1) v = geluf(v);
                if constexpr (OUTBF==1){
                    ((unsigned short*)Cv)[(size_t)row*ldc + col] = f2bf(v);
                } else {
                    float* cp = (float*)Cv + (size_t)row*ldc + col;
                    if (ADD) v += *cp;
                    *cp = v;
                }
            }
        }
    }
}

// ---------------------------------------------------------------------------
// fp32 -> bf16 flat cast, 8 elems/thread.
// ---------------------------------------------------------------------------
__launch_bounds__(256)
__global__ void cast_bf16_kernel(const float* __restrict__ in, unsigned short* __restrict__ out)
{
    size_t i = (size_t)blockIdx.x*256 + threadIdx.x;
    const float4 v0 = reinterpret_cast<const float4*>(in)[i*2];
    const float4 v1 = reinterpret_cast<const float4*>(in)[i*2+1];
    union { unsigned short u[8]; bf8v v; } o;
    o.u[0]=f2bf(v0.x); o.u[1]=f2bf(v0.y); o.u[2]=f2bf(v0.z); o.u[3]=f2bf(v0.w);
    o.u[4]=f2bf(v1.x); o.u[5]=f2bf(v1.y); o.u[6]=f2bf(v1.z); o.u[7]=f2bf(v1.w);
    reinterpret_cast<bf8v*>(out)[i] = o.v;
}

// ---------------------------------------------------------------------------
// fp32 [K][N] -> bf16 [N][K] cast + transpose, 64x64 LDS tiles.
// ---------------------------------------------------------------------------
__launch_bounds__(256)
__global__ void castT_kernel(const float* __restrict__ in, unsigned short* __restrict__ out,
                             int Kd, int N)
{
    __shared__ float t[64][65];
    int k0 = blockIdx.y*64, n0 = blockIdx.x*64;
    int c = threadIdx.x & 63, r4 = threadIdx.x >> 6;
    #pragma unroll
    for (int it=0; it<16; it++){
        int row = it*4 + r4;
        t[row][c] = in[(size_t)(k0+row)*N + n0 + c];
    }
    __syncthreads();
    #pragma unroll
    for (int it=0; it<16; it++){
        int row = it*4 + r4;
        out[(size_t)(n0+row)*Kd + k0 + c] = f2bf(t[c][row]);
    }
}

// ---------------------------------------------------------------------------
// RMSNorm -> bf16 out: one wave per token
// ---------------------------------------------------------------------------
__launch_bounds__(256)
__global__ void rms_bf_kernel(const float* __restrict__ x, const float* __restrict__ w,
                              unsigned short* __restrict__ out)
{
    int tid = threadIdx.x;
    int lane = tid & 63, wv = tid >> 6;
    int token = blockIdx.x*4 + wv;
    const float* xr = x + (size_t)token*DD;
    float v0 = xr[lane], v1 = xr[lane+64];
    float ss = v0*v0 + v1*v1;
    #pragma unroll
    for (int off=32; off>0; off>>=1) ss += __shfl_xor(ss, off);
    float r = rsqrtf(ss*(1.0f/DD) + 1e-5f);
    unsigned short* o = out + (size_t)token*DD;
    o[lane]    = f2bf(v0*r*w[lane]);
    o[lane+64] = f2bf(v1*r*w[lane+64]);
}

// ---------------------------------------------------------------------------
// Depthwise causal conv (K=4) + bias + silu.
// ---------------------------------------------------------------------------
__launch_bounds__(256)
__global__ void conv_kernel(const float* __restrict__ hg, const float* __restrict__ cw,
                            const float* __restrict__ cb, float* __restrict__ hc)
{
    int idx = blockIdx.x*256 + threadIdx.x;
    int i = idx & (II-1);
    int m = idx >> 8;
    int s = m & (SQ-1);
    const float* w = cw + i*KKs;
    float a = cb[i];
    #pragma unroll
    for (int k=0;k<KKs;k++){
        int ssrc = s + k - (KKs-1);
        if (ssrc >= 0) a += hg[(size_t)(m + k - (KKs-1))*(2*II) + i] * w[k];
    }
    hc[idx] = siluf(a);
}

// ---------------------------------------------------------------------------
// Fused x_proj + dt_proj + softplus + B/C extraction. fp32 throughout.
// ---------------------------------------------------------------------------
#define XT 16
__launch_bounds__(256)
__global__ void xproj_fused_kernel(const float* __restrict__ hconv,
                                   const float* __restrict__ xpw,
                                   const float* __restrict__ dtw,
                                   const float* __restrict__ dtb,
                                   float* __restrict__ dt_out,
                                   float* __restrict__ bc)
{
    __shared__ float sh[XT][II+4];
    __shared__ float ssm_s[XT][40];
    const int tid = threadIdx.x;
    const int m0 = blockIdx.x * XT;

    {
        const float4* src = reinterpret_cast<const float4*>(hconv + (size_t)m0*II);
        #pragma unroll
        for (int e=0;e<4;e++){
            int idx = e*256 + tid;
            int t = idx >> 6, c = idx & 63;
            *reinterpret_cast<float4*>(&sh[t][c*4]) = src[idx];
        }
    }
    __syncthreads();

    for (int e = tid; e < XT*40; e += 256){
        int t = e / 40, o = e - t*40;
        float a0=0.f, a1=0.f, a2=0.f, a3=0.f;
        #pragma unroll 16
        for (int k=0;k<II;k+=4){
            float4 h4 = *reinterpret_cast<const float4*>(&sh[t][k]);
            a0 += h4.x*xpw[(k+0)*40+o];
            a1 += h4.y*xpw[(k+1)*40+o];
            a2 += h4.z*xpw[(k+2)*40+o];
            a3 += h4.w*xpw[(k+3)*40+o];
        }
        ssm_s[t][o] = (a0+a1)+(a2+a3);
    }
    __syncthreads();

    #pragma unroll
    for (int e = tid; e < XT*32; e += 256){
        int t = e >> 5, n = e & 31;
        bc[(size_t)(m0+t)*32 + n] = ssm_s[t][8+n];
    }

    {
        const int i = tid;
        float wr[RRs];
        #pragma unroll
        for (int r=0;r<RRs;r++) wr[r] = dtw[r*II + i];
        const float bb = dtb[i];
        #pragma unroll 4
        for (int t=0;t<XT;t++){
            float a = bb;
            #pragma unroll
            for (int r=0;r<RRs;r++) a += ssm_s[t][r]*wr[r];
            dt_out[(size_t)(m0+t)*II + i] = softplusf(a);
        }
    }
}

// ---------------------------------------------------------------------------
// Selective scan, LDS-chunked (unchanged).
// ---------------------------------------------------------------------------
__launch_bounds__(256)
__global__ void scan_kernel(const float* __restrict__ dtp, const float* __restrict__ bc,
                            const float* __restrict__ hconv, const float* __restrict__ hg,
                            const float* __restrict__ A_log, const float* __restrict__ D_par,
                            unsigned short* __restrict__ ybf)
{
    __shared__ float sdt[16][17], shv[16][17], sgv[16][17], sbc[16][33];
    int b = blockIdx.x >> 4, chunk = blockIdx.x & 15;
    int tid = threadIdx.x;
    int n = tid & 15, il = tid >> 4;
    int i = chunk*16 + il;
    float A2 = -__expf(A_log[i*NNs + n]) * 1.44269504f;
    float carry = 0.0f;
    const float dpi = D_par[i];
    const int m0 = b*SQ;
    const int li = tid & 15, ls = tid >> 4;
    const int gi = chunk*16 + li;
    for (int cs=0; cs<16; cs++){
        __syncthreads();
        int mload = m0 + cs*16 + ls;
        sdt[ls][li] = dtp[(size_t)mload*II + gi];
        shv[ls][li] = hconv[(size_t)mload*II + gi];
        sgv[ls][li] = hg[(size_t)mload*(2*II) + II + gi];
        sbc[ls][li]      = bc[(size_t)mload*32 + li];
        sbc[ls][li + 16] = bc[(size_t)mload*32 + 16 + li];
        __syncthreads();
        #pragma unroll
        for (int s=0; s<16; s++){
            float dtv = sdt[s][il];
            float hv  = shv[s][il];
            float dA  = exp2f(dtv*A2);
            carry = carry*dA + dtv*hv*sbc[s][n];
            float acc = carry*sbc[s][16+n];
            acc += __shfl_xor(acc, 1);
            acc += __shfl_xor(acc, 2);
            acc += __shfl_xor(acc, 4);
            acc += __shfl_xor(acc, 8);
            if (n == 0){
                ybf[(size_t)(m0 + cs*16 + s)*II + i] =
                    f2bf((acc + hv*dpi) * siluf(sgv[s][il]));
            }
        }
    }
}

// ---------------------------------------------------------------------------
// Head per batch + KL (unchanged).
// ---------------------------------------------------------------------------
__launch_bounds__(128)
__global__ void head_kernel(const float* __restrict__ x, const float* __restrict__ normf,
                            const float* __restrict__ mu_w, const float* __restrict__ mu_b,
                            const float* __restrict__ lv_w, const float* __restrict__ lv_b,
                            const float* __restrict__ eps, const float* __restrict__ h1_w,
                            const float* __restrict__ h1_b, const float* __restrict__ h2_w,
                            const float* __restrict__ h2_b, float* __restrict__ out,
                            float* __restrict__ klacc)
{
    __shared__ float lasts[DD];
    __shared__ float zs[DD];
    __shared__ float hr[256];
    __shared__ float red[2];
    int b = blockIdx.x, d = threadIdx.x;
    int lane = d & 63, wv = d >> 6;
    float xv = x[((size_t)(b*SQ + SQ-1))*DD + d];
    float ss = xv*xv;
    #pragma unroll
    for (int off=32; off>0; off>>=1) ss += __shfl_xor(ss, off);
    if (lane==0) red[wv] = ss;
    __syncthreads();
    float tot = red[0] + red[1];
    float last = xv * rsqrtf(tot*(1.0f/DD) + 1e-5f) * normf[d];
    lasts[d] = last;
    __syncthreads();
    float mu = mu_b[d], lv = lv_b[d];
    for (int j=0;j<DD;j++){
        float lj = lasts[j];
        mu += lj*mu_w[j*DD + d];
        lv += lj*lv_w[j*DD + d];
    }
    float z = mu + eps[b*ZZs + d]*__expf(0.5f*lv);
    zs[d] = z;
    float klp = 1.0f + lv - mu*mu - __expf(lv);
    #pragma unroll
    for (int off=32; off>0; off>>=1) klp += __shfl_xor(klp, off);
    if (lane==0) red[wv] = klp;
    __syncthreads();
    if (d==0) atomicAdd(klacc, red[0]+red[1]);
    for (int o=d; o<256; o+=128){
        float a = h1_b[o];
        for (int j=0;j<DD;j++) a += zs[j]*h1_w[j*256 + o];
        hr[o] = fmaxf(a, 0.0f);
    }
    __syncthreads();
    if (d < 40){
        float a = h2_b[d];
        for (int k=0;k<256;k++) a += hr[k]*h2_w[k*40 + d];
        out[b*(FUTs*2) + d] = a;
    }
}

__global__ void kl_final_kernel(const float* __restrict__ klacc, float* __restrict__ out)
{
    out[0] = -0.5f * klacc[0] * (1.0f/(BQ*ZZs));
}

// ---------------------------------------------------------------------------
extern "C" void kernel_launch(void* const* d_in, const int* in_sizes, int n_in,
                              void* d_out, int out_size, void* d_ws, size_t ws_size,
                              hipStream_t stream)
{
    const float* x_cam     = (const float*)d_in[0];
    const float* x_ego     = (const float*)d_in[1];
    const float* vib_eps   = (const float*)d_in[2];
    const float* vis_w1    = (const float*)d_in[3];
    const float* vis_b1    = (const float*)d_in[4];
    const float* vis_w2    = (const float*)d_in[5];
    const float* vis_b2    = (const float*)d_in[6];
    const float* ego_w     = (const float*)d_in[7];
    const float* ego_b     = (const float*)d_in[8];
    const float* fus_w     = (const float*)d_in[9];
    const float* fus_b     = (const float*)d_in[10];
    const float* norm_w    = (const float*)d_in[11];
    const float* in_proj_w = (const float*)d_in[12];
    const float* conv_w    = (const float*)d_in[13];
    const float* conv_b    = (const float*)d_in[14];
    const float* x_proj_w  = (const float*)d_in[15];
    const float* dt_proj_w = (const float*)d_in[16];
    const float* dt_proj_b = (const float*)d_in[17];
    const float* A_log     = (const float*)d_in[18];
    const float* D_par     = (const float*)d_in[19];
    const float* out_proj_w= (const float*)d_in[20];
    const float* normf_w   = (const float*)d_in[21];
    const float* mu_w      = (const float*)d_in[22];
    const float* mu_b      = (const float*)d_in[23];
    const float* lv_w      = (const float*)d_in[24];
    const float* lv_b      = (const float*)d_in[25];
    const float* h1_w      = (const float*)d_in[26];
    const float* h1_b      = (const float*)d_in[27];
    const float* h2_w      = (const float*)d_in[28];
    const float* h2_b      = (const float*)d_in[29];

    float* ws = (float*)d_ws;
    float* hg    = ws;                                        // 8192*512 fp32
    unsigned short* v1g  = (unsigned short*)hg;               // 8192*512 bf16 (alias)
    float* hconv = ws + 4194304;                              // 8192*256 fp32
    unsigned short* catbf = (unsigned short*)hconv;           // 8192*256 bf16 (alias)
    float* xbuf  = ws + 6291456;                              // 8192*128
    float* dtws  = ws + 7340032;                              // 8192*256
    float* bcws  = ws + 9437184;                              // 8192*32
    unsigned short* ybf  = (unsigned short*)(ws + 9699328);   // 8192*256 bf16
    unsigned short* xnbf = (unsigned short*)(ws + 10747904);  // 8192*128 bf16
    unsigned short* w1t  = (unsigned short*)(ws + 11272192);  // 512*8192 bf16
    unsigned short* w2t  = (unsigned short*)(ws + 13369344);  // 128*512  bf16
    unsigned short* egot = (unsigned short*)(ws + 13402112);  // 128*64   bf16
    unsigned short* fust = (unsigned short*)(ws + 13406208);  // 128*256  bf16
    unsigned short* wipt = (unsigned short*)(ws + 13422592);  // 4*512*128 bf16
    unsigned short* wopt = (unsigned short*)(ws + 13553664);  // 4*128*256 bf16
    float* klacc = ws + 13619200;
    unsigned short* xcbf = (unsigned short*)(ws + 13619208);  // 8192*8192 bf16
    const size_t need_bytes = (size_t)(13619208 + 33554432) * 4;
    const bool big_ws = (ws_size >= need_bytes);

    hipMemsetAsync(klacc, 0, sizeof(float), stream);

    // ---- weight casts: bf16 + transpose to [N][K] ----
    castT_kernel<<<dim3(8, 128), 256, 0, stream>>>(vis_w1, w1t, 8192, 512);
    castT_kernel<<<dim3(2, 8),   256, 0, stream>>>(vis_w2, w2t, 512, 128);
    castT_kernel<<<dim3(2, 1),   256, 0, stream>>>(ego_w,  egot, 64, 128);
    castT_kernel<<<dim3(2, 4),   256, 0, stream>>>(fus_w,  fust, 256, 128);
    for (int l=0; l<LLs; l++){
        castT_kernel<<<dim3(8, 2), 256, 0, stream>>>(
            in_proj_w + (size_t)l*DD*2*II, wipt + (size_t)l*2*II*DD, DD, 2*II);
        castT_kernel<<<dim3(2, 4), 256, 0, stream>>>(
            out_proj_w + (size_t)l*II*DD, wopt + (size_t)l*DD*II, II, DD);
    }

    // 1) vision GEMM1: gelu(x_cam @ W1 + b1) -> v1g (bf16 out)
    if (big_ws){
        cast_bf16_kernel<<<32768, 256, 0, stream>>>(x_cam, xcbf);   // 67M elems
        gemm_lds128_kernel<1,0,1><<<dim3(64, 4), 256, 0, stream>>>(
            xcbf, w1t, vis_b1, v1g, MTOK, 512, 8192, 512);
    } else {
        gemm_bf16_kernel<1,0,1,float><<<dim3(64, 8), 256, 0, stream>>>(
            x_cam, w1t, vis_b1, v1g, MTOK, 512, 8192, 512);
    }
    // 2) v2 = v1g @ W2 + b2 -> catbf[:, :128] (bf16 out)
    gemm_lds_kernel<0,0,1><<<dim3(64, 2), 256, 0, stream>>>(
        v1g, w2t, vis_b2, catbf, MTOK, 128, 512, 256);
    // 3) e = x_ego @ ego_w + b -> catbf[:, 128:]  (fp32 A, K=64 -> legacy)
    gemm_bf16_kernel<0,0,1,float><<<dim3(64, 2), 256, 0, stream>>>(
        x_ego, egot, ego_b, catbf + 128, MTOK, 128, 64, 256);
    // 4) fused = gelu(catbf @ fus_w + b) -> xbuf (fp32 residual stream)
    gemm_lds_kernel<1,0,0><<<dim3(64, 2), 256, 0, stream>>>(
        catbf, fust, fus_b, xbuf, MTOK, 128, 256, 128);

    for (int l=0; l<LLs; l++){
        rms_bf_kernel<<<MTOK/4, 256, 0, stream>>>(xbuf, norm_w + l*DD, xnbf);
        gemm_lds128_kernel<0,0,0><<<dim3(64, 4), 256, 0, stream>>>(
            xnbf, wipt + (size_t)l*2*II*DD, nullptr, hg, MTOK, 2*II, DD, 2*II);
        conv_kernel<<<MTOK*II/256, 256, 0, stream>>>(
            hg, conv_w + (size_t)l*II*KKs, conv_b + (size_t)l*II, hconv);
        xproj_fused_kernel<<<MTOK/XT, 256, 0, stream>>>(
            hconv, x_proj_w + (size_t)l*II*40, dt_proj_w + (size_t)l*RRs*II,
            dt_proj_b + (size_t)l*II, dtws, bcws);
        scan_kernel<<<BQ*16, 256, 0, stream>>>(
            dtws, bcws, hconv, hg, A_log + (size_t)l*II*NNs, D_par + (size_t)l*II, ybf);
        gemm_lds_kernel<0,1,0><<<dim3(64, 2), 256, 0, stream>>>(
            ybf, wopt + (size_t)l*DD*II, nullptr, xbuf, MTOK, DD, II, DD);
    }

    head_kernel<<<BQ, 128, 0, stream>>>(
        xbuf, normf_w, mu_w, mu_b, lv_w, lv_b, vib_eps,
        h1_w, h1_b, h2_w, h2_b, (float*)d_out, klacc);
    kl_final_kernel<<<1, 1, 0, stream>>>(klacc, (float*)d_out + 1280);
}

// Round 5
// 1227.785 us; speedup vs baseline: 1.0184x; 1.0184x over previous
//
#include <hip/hip_runtime.h>
#include <hip/hip_bf16.h>
#include <math.h>

#define BQ 32
#define SQ 256
#define MTOK 8192       // B*S
#define DD 128
#define II 256
#define NNs 16
#define RRs 8
#define KKs 4
#define LLs 4
#define ZZs 128
#define FUTs 20

typedef __attribute__((ext_vector_type(8))) short bf8v;   // 8 bf16 (4 VGPRs)
typedef __attribute__((ext_vector_type(4))) float f4v;    // 4 fp32 acc

__device__ __forceinline__ float geluf(float x){ return 0.5f*x*(1.0f+erff(x*0.70710678118654752f)); }
__device__ __forceinline__ float siluf(float x){ return x/(1.0f+__expf(-x)); }
__device__ __forceinline__ float softplusf(float x){ return fmaxf(x,0.0f)+log1pf(__expf(-fabsf(x))); }
__device__ __forceinline__ unsigned short f2bf(float x){
    __hip_bfloat16 h = __float2bfloat16(x);
    return *reinterpret_cast<unsigned short*>(&h);
}

// async global -> LDS, 16B per lane. LDS dest is wave-uniform base + lane*16.
__device__ __forceinline__ void gload_lds16(const void* g, void* l){
    __builtin_amdgcn_global_load_lds(
        (const __attribute__((address_space(1))) void*)g,
        (__attribute__((address_space(3))) void*)l, 16, 0, 0);
}

// counted-vmcnt wait + workgroup barrier (T4: never drain to 0 mid-loop).
#define PIPE_WAIT_BAR(N) do {                                   \
    __builtin_amdgcn_sched_barrier(0);                          \
    asm volatile("s_waitcnt vmcnt(" #N ")" ::: "memory");       \
    __builtin_amdgcn_s_barrier();                               \
    __builtin_amdgcn_sched_barrier(0);                          \
} while(0)

#define PIPE_END_BAR() do {                                     \
    __builtin_amdgcn_sched_barrier(0);                          \
    asm volatile("s_waitcnt lgkmcnt(0)" ::: "memory");          \
    __builtin_amdgcn_s_barrier();                               \
    __builtin_amdgcn_sched_barrier(0);                          \
} while(0)

// ---------------------------------------------------------------------------
// 512-thread bf16 GEMM: BM=BN=128, BK=64, 8 waves (2M x 4N), each wave owns
// a 64x32 sub-tile (acc[4][2]). Rationale (R4 post-mortem): R2/R3 both hit
// 1.61GB/172us = 9.3 TB/s aggregate VMEM (a fabric/L3 ceiling); BN=128
// halves traffic to 1.07GB, and 8 waves/block restores 2 waves/SIMD of TLP
// that R4's 4-wave version lost (Occupancy 11.7% -> regression).
// 3-buffer LDS ring (96KB, 1 block/CU), counted-vmcnt pipeline:
// 4 loads/stage/wave -> waits 8/4/0. XOR swizzle as R2 (conflicts = 0).
// Requires Kd%64==0, Kd>=128, M%128==0, N%128==0. Grid (M/128, N/128).
// ---------------------------------------------------------------------------
template<int ACT,int ADD,int OUTBF>
__launch_bounds__(512,1)
__global__ void gemm_w512_kernel(const unsigned short* __restrict__ A,
                                 const unsigned short* __restrict__ Bt,
                                 const float* __restrict__ bias,
                                 void* __restrict__ Cv,
                                 int M, int N, int Kd, int ldc)
{
    __shared__ __align__(16) unsigned short As[3][128*64];
    __shared__ __align__(16) unsigned short Bs[3][128*64];
    const int tid = threadIdx.x;
    const int w = tid >> 6, lane = tid & 63;
    const int ml = lane & 15, quad = lane >> 4;
    const int wm = w >> 2, wn = w & 3;            // 2M x 4N wave grid
    const int rowBase = blockIdx.x * 128, colBase = blockIdx.y * 128;

    const int srow = lane >> 3;                   // row within 8-row chunk
    const int scol = (((lane&7) ^ (lane>>3)))*8;  // PRE-SWIZZLED global col

    f4v acc[4][2];
    #pragma unroll
    for (int i=0;i<4;i++)
      #pragma unroll
      for (int j=0;j<2;j++) acc[i][j] = (f4v){0.f,0.f,0.f,0.f};

    auto stage = [&](int buf, int kt){
        #pragma unroll
        for (int e=0;e<2;e++){
            const int c = w*2 + e;                // chunk 0..15 (8 rows each)
            const unsigned short* srcA = A + (size_t)(rowBase + c*8 + srow)*Kd + kt + scol;
            gload_lds16(srcA, (unsigned short*)As[buf] + c*512);
            const unsigned short* srcB = Bt + (size_t)(colBase + c*8 + srow)*Kd + kt + scol;
            gload_lds16(srcB, (unsigned short*)Bs[buf] + c*512);
        }
    };

    const int swz = (ml&7)*8;                     // read-side XOR (elems)

    auto compute = [&](int buf){
        #pragma unroll
        for (int ks=0; ks<2; ks++){
            const int co = (ks*32 + quad*8) ^ swz;
            bf8v a[4], b[2];
            #pragma unroll
            for (int mf=0; mf<4; mf++)
                a[mf] = *reinterpret_cast<const bf8v*>(&As[buf][(wm*64 + mf*16 + ml)*64 + co]);
            #pragma unroll
            for (int nf=0; nf<2; nf++)
                b[nf] = *reinterpret_cast<const bf8v*>(&Bs[buf][(wn*32 + nf*16 + ml)*64 + co]);
            #pragma unroll
            for (int mf=0; mf<4; mf++)
                #pragma unroll
                for (int nf=0; nf<2; nf++)
                    acc[mf][nf] = __builtin_amdgcn_mfma_f32_16x16x32_bf16(a[mf], b[nf], acc[mf][nf], 0,0,0);
        }
    };

    const int nIter = Kd >> 6;                    // >= 2 at every call site
    stage(0, 0);
    stage(1, 64);                                 // 8 loads/wave in flight

    int i = 0;
    for (; i + 2 < nIter; ++i){
        stage((i+2)%3, (i+2)<<6);                 // 12 in flight
        PIPE_WAIT_BAR(8);                         // tile i landed; 8 stay
        compute(i%3);
        PIPE_END_BAR();                           // reads done before reuse
    }
    // i == nIter-2
    PIPE_WAIT_BAR(4);                             // tile nIter-2 landed
    compute(i%3);
    PIPE_END_BAR();
    ++i;
    PIPE_WAIT_BAR(0);                             // tile nIter-1 landed
    compute(i%3);

    #pragma unroll
    for (int mf=0; mf<4; mf++){
        #pragma unroll
        for (int nf=0; nf<2; nf++){
            int col = colBase + wn*32 + nf*16 + ml;
            float bb = bias ? bias[col] : 0.0f;
            #pragma unroll
            for (int r=0;r<4;r++){
                int row = rowBase + wm*64 + mf*16 + quad*4 + r;
                float v = acc[mf][nf][r] + bb;
                if (ACT==1) v = geluf(v);
                if constexpr (OUTBF==1){
                    ((unsigned short*)Cv)[(size_t)row*ldc + col] = f2bf(v);
                } else {
                    float* cp = (float*)Cv + (size_t)row*ldc + col;
                    if (ADD) v += *cp;
                    *cp = v;
                }
            }
        }
    }
}

// ---------------------------------------------------------------------------
// BM=BN=64 bf16 GEMM for N=128 outputs: grid (M/64, N/64) = 256 blocks at
// M=8192,N=128 -> FULL CU coverage (old BM=128 grid was 128 blocks = half
// the chip idle). 256 threads, 4 waves, each wave a 16x64 row-slice
// (acc[1][4]). Same 3-buffer counted-vmcnt ring (48KB LDS), same swizzle.
// ---------------------------------------------------------------------------
template<int ACT,int ADD,int OUTBF>
__launch_bounds__(256,2)
__global__ void gemm_lds64_kernel(const unsigned short* __restrict__ A,
                                  const unsigned short* __restrict__ Bt,
                                  const float* __restrict__ bias,
                                  void* __restrict__ Cv,
                                  int M, int N, int Kd, int ldc)
{
    __shared__ __align__(16) unsigned short As[3][64*64];
    __shared__ __align__(16) unsigned short Bs[3][64*64];
    const int tid = threadIdx.x;
    const int w = tid >> 6, lane = tid & 63;
    const int ml = lane & 15, quad = lane >> 4;
    const int rowBase = blockIdx.x * 64, colBase = blockIdx.y * 64;

    const int srow = lane >> 3;
    const int scol = (((lane&7) ^ (lane>>3)))*8;

    f4v acc[4];
    #pragma unroll
    for (int j=0;j<4;j++) acc[j] = (f4v){0.f,0.f,0.f,0.f};

    auto stage = [&](int buf, int kt){
        #pragma unroll
        for (int e=0;e<2;e++){
            const int c = w*2 + e;                // chunk 0..7 (8 rows each)
            const unsigned short* srcA = A + (size_t)(rowBase + c*8 + srow)*Kd + kt + scol;
            gload_lds16(srcA, (unsigned short*)As[buf] + c*512);
            const unsigned short* srcB = Bt + (size_t)(colBase + c*8 + srow)*Kd + kt + scol;
            gload_lds16(srcB, (unsigned short*)Bs[buf] + c*512);
        }
    };

    const int swz = (ml&7)*8;

    auto compute = [&](int buf){
        #pragma unroll
        for (int ks=0; ks<2; ks++){
            const int co = (ks*32 + quad*8) ^ swz;
            bf8v a0 = *reinterpret_cast<const bf8v*>(&As[buf][(w*16 + ml)*64 + co]);
            #pragma unroll
            for (int nt=0; nt<4; nt++){
                bf8v b = *reinterpret_cast<const bf8v*>(&Bs[buf][(nt*16+ml)*64 + co]);
                acc[nt] = __builtin_amdgcn_mfma_f32_16x16x32_bf16(a0, b, acc[nt], 0,0,0);
            }
        }
    };

    const int nIter = Kd >> 6;                    // >= 2 at every call site
    stage(0, 0);
    stage(1, 64);

    int i = 0;
    for (; i + 2 < nIter; ++i){
        stage((i+2)%3, (i+2)<<6);
        PIPE_WAIT_BAR(8);
        compute(i%3);
        PIPE_END_BAR();
    }
    PIPE_WAIT_BAR(4);
    compute(i%3);
    PIPE_END_BAR();
    ++i;
    PIPE_WAIT_BAR(0);
    compute(i%3);

    #pragma unroll
    for (int nt=0; nt<4; nt++){
        int col = colBase + nt*16 + ml;
        float bb = bias ? bias[col] : 0.0f;
        #pragma unroll
        for (int r=0;r<4;r++){
            int row = rowBase + w*16 + quad*4 + r;
            float v = acc[nt][r] + bb;
            if (ACT==1) v = geluf(v);
            if constexpr (OUTBF==1){
                ((unsigned short*)Cv)[(size_t)row*ldc + col] = f2bf(v);
            } else {
                float* cp = (float*)Cv + (size_t)row*ldc + col;
                if (ADD) v += *cp;
                *cp = v;
            }
        }
    }
}

// ---------------------------------------------------------------------------
// Legacy reg-staged GEMM (fp32 or bf16 A). Kept for GEMM3 (fp32 x_ego, K=64)
// and as the GEMM1 fallback when ws_size can't hold the bf16 x_cam cast.
// ---------------------------------------------------------------------------
template<int ACT,int ADD,int OUTBF,typename AT>
__launch_bounds__(256,2)
__global__ void gemm_bf16_kernel(const AT* __restrict__ A,
                                 const unsigned short* __restrict__ Bt,
                                 const float* __restrict__ bias,
                                 void* __restrict__ Cv,
                                 int M, int N, int Kd, int ldc)
{
    constexpr int LDK = 72;
    __shared__ unsigned short As[128*LDK];
    __shared__ unsigned short Bs[64*LDK];
    const int tid = threadIdx.x;
    const int w = tid >> 6, lane = tid & 63;
    const int ml = lane & 15, quad = lane >> 4;
    const int rowBase = blockIdx.x * 128, colBase = blockIdx.y * 64;

    f4v acc[2][4];
    #pragma unroll
    for (int i=0;i<2;i++)
      #pragma unroll
      for (int j=0;j<4;j++) acc[i][j] = (f4v){0.f,0.f,0.f,0.f};

    bf8v pa[4], pb[2];
    const int ar = tid >> 3, as8 = (tid & 7) * 8;

    auto loadTile = [&](int kt){
        #pragma unroll
        for (int e=0;e<4;e++){
            int r = ar + e*32;
            if constexpr (sizeof(AT)==2){
                pa[e] = *reinterpret_cast<const bf8v*>(
                    (const unsigned short*)A + (size_t)(rowBase+r)*Kd + kt + as8);
            } else {
                const float* ap = (const float*)A + (size_t)(rowBase+r)*Kd + kt + as8;
                float4 v0 = *reinterpret_cast<const float4*>(ap);
                float4 v1 = *reinterpret_cast<const float4*>(ap+4);
                union { unsigned short u[8]; bf8v v; } o;
                o.u[0]=f2bf(v0.x); o.u[1]=f2bf(v0.y); o.u[2]=f2bf(v0.z); o.u[3]=f2bf(v0.w);
                o.u[4]=f2bf(v1.x); o.u[5]=f2bf(v1.y); o.u[6]=f2bf(v1.z); o.u[7]=f2bf(v1.w);
                pa[e] = o.v;
            }
        }
        #pragma unroll
        for (int e=0;e<2;e++){
            int r = ar + e*32;
            pb[e] = *reinterpret_cast<const bf8v*>(
                Bt + (size_t)(colBase+r)*Kd + kt + as8);
        }
    };

    loadTile(0);

    for (int kt=0; kt<Kd; kt+=64){
        #pragma unroll
        for (int e=0;e<4;e++) *reinterpret_cast<bf8v*>(&As[(ar+e*32)*LDK + as8]) = pa[e];
        #pragma unroll
        for (int e=0;e<2;e++) *reinterpret_cast<bf8v*>(&Bs[(ar+e*32)*LDK + as8]) = pb[e];
        __syncthreads();
        if (kt + 64 < Kd) loadTile(kt + 64);
        #pragma unroll
        for (int ks=0; ks<2; ks++){
            bf8v a0 = *reinterpret_cast<bf8v*>(&As[(w*32 +      ml)*LDK + ks*32 + quad*8]);
            bf8v a1 = *reinterpret_cast<bf8v*>(&As[(w*32 + 16 + ml)*LDK + ks*32 + quad*8]);
            #pragma unroll
            for (int nt=0; nt<4; nt++){
                bf8v b = *reinterpret_cast<bf8v*>(&Bs[(nt*16+ml)*LDK + ks*32 + quad*8]);
                acc[0][nt] = __builtin_amdgcn_mfma_f32_16x16x32_bf16(a0, b, acc[0][nt], 0,0,0);
                acc[1][nt] = __builtin_amdgcn_mfma_f32_16x16x32_bf16(a1, b, acc[1][nt], 0,0,0);
            }
        }
        __syncthreads();
    }

    #pragma unroll
    for (int mt=0; mt<2; mt++){
        #pragma unroll
        for (int nt=0; nt<4; nt++){
            int col = colBase + nt*16 + ml;
            float bb = bias ? bias[col] : 0.0f;
            #pragma unroll
            for (int r=0;r<4;r++){
                int row = rowBase + w*32 + mt*16 + quad*4 + r;
                float v = acc[mt][nt][r] + bb;
                if (ACT==1) v = geluf(v);
                if constexpr (OUTBF==1){
                    ((unsigned short*)Cv)[(size_t)row*ldc + col] = f2bf(v);
                } else {
                    float* cp = (float*)Cv + (size_t)row*ldc + col;
                    if (ADD) v += *cp;
                    *cp = v;
                }
            }
        }
    }
}

// ---------------------------------------------------------------------------
// fp32 -> bf16 flat cast, 8 elems/thread.
// ---------------------------------------------------------------------------
__launch_bounds__(256)
__global__ void cast_bf16_kernel(const float* __restrict__ in, unsigned short* __restrict__ out)
{
    size_t i = (size_t)blockIdx.x*256 + threadIdx.x;
    const float4 v0 = reinterpret_cast<const float4*>(in)[i*2];
    const float4 v1 = reinterpret_cast<const float4*>(in)[i*2+1];
    union { unsigned short u[8]; bf8v v; } o;
    o.u[0]=f2bf(v0.x); o.u[1]=f2bf(v0.y); o.u[2]=f2bf(v0.z); o.u[3]=f2bf(v0.w);
    o.u[4]=f2bf(v1.x); o.u[5]=f2bf(v1.y); o.u[6]=f2bf(v1.z); o.u[7]=f2bf(v1.w);
    reinterpret_cast<bf8v*>(out)[i] = o.v;
}

// ---------------------------------------------------------------------------
// fp32 [K][N] -> bf16 [N][K] cast + transpose, 64x64 LDS tiles.
// ---------------------------------------------------------------------------
__launch_bounds__(256)
__global__ void castT_kernel(const float* __restrict__ in, unsigned short* __restrict__ out,
                             int Kd, int N)
{
    __shared__ float t[64][65];
    int k0 = blockIdx.y*64, n0 = blockIdx.x*64;
    int c = threadIdx.x & 63, r4 = threadIdx.x >> 6;
    #pragma unroll
    for (int it=0; it<16; it++){
        int row = it*4 + r4;
        t[row][c] = in[(size_t)(k0+row)*N + n0 + c];
    }
    __syncthreads();
    #pragma unroll
    for (int it=0; it<16; it++){
        int row = it*4 + r4;
        out[(size_t)(n0+row)*Kd + k0 + c] = f2bf(t[c][row]);
    }
}

// ---------------------------------------------------------------------------
// RMSNorm -> bf16 out: one wave per token
// ---------------------------------------------------------------------------
__launch_bounds__(256)
__global__ void rms_bf_kernel(const float* __restrict__ x, const float* __restrict__ w,
                              unsigned short* __restrict__ out)
{
    int tid = threadIdx.x;
    int lane = tid & 63, wv = tid >> 6;
    int token = blockIdx.x*4 + wv;
    const float* xr = x + (size_t)token*DD;
    float v0 = xr[lane], v1 = xr[lane+64];
    float ss = v0*v0 + v1*v1;
    #pragma unroll
    for (int off=32; off>0; off>>=1) ss += __shfl_xor(ss, off);
    float r = rsqrtf(ss*(1.0f/DD) + 1e-5f);
    unsigned short* o = out + (size_t)token*DD;
    o[lane]    = f2bf(v0*r*w[lane]);
    o[lane+64] = f2bf(v1*r*w[lane+64]);
}

// ---------------------------------------------------------------------------
// Depthwise causal conv (K=4) + bias + silu.
// ---------------------------------------------------------------------------
__launch_bounds__(256)
__global__ void conv_kernel(const float* __restrict__ hg, const float* __restrict__ cw,
                            const float* __restrict__ cb, float* __restrict__ hc)
{
    int idx = blockIdx.x*256 + threadIdx.x;
    int i = idx & (II-1);
    int m = idx >> 8;
    int s = m & (SQ-1);
    const float* w = cw + i*KKs;
    float a = cb[i];
    #pragma unroll
    for (int k=0;k<KKs;k++){
        int ssrc = s + k - (KKs-1);
        if (ssrc >= 0) a += hg[(size_t)(m + k - (KKs-1))*(2*II) + i] * w[k];
    }
    hc[idx] = siluf(a);
}

// ---------------------------------------------------------------------------
// Fused x_proj + dt_proj + softplus + B/C extraction. fp32 throughout.
// ---------------------------------------------------------------------------
#define XT 16
__launch_bounds__(256)
__global__ void xproj_fused_kernel(const float* __restrict__ hconv,
                                   const float* __restrict__ xpw,
                                   const float* __restrict__ dtw,
                                   const float* __restrict__ dtb,
                                   float* __restrict__ dt_out,
                                   float* __restrict__ bc)
{
    __shared__ float sh[XT][II+4];
    __shared__ float ssm_s[XT][40];
    const int tid = threadIdx.x;
    const int m0 = blockIdx.x * XT;

    {
        const float4* src = reinterpret_cast<const float4*>(hconv + (size_t)m0*II);
        #pragma unroll
        for (int e=0;e<4;e++){
            int idx = e*256 + tid;
            int t = idx >> 6, c = idx & 63;
            *reinterpret_cast<float4*>(&sh[t][c*4]) = src[idx];
        }
    }
    __syncthreads();

    for (int e = tid; e < XT*40; e += 256){
        int t = e / 40, o = e - t*40;
        float a0=0.f, a1=0.f, a2=0.f, a3=0.f;
        #pragma unroll 16
        for (int k=0;k<II;k+=4){
            float4 h4 = *reinterpret_cast<const float4*>(&sh[t][k]);
            a0 += h4.x*xpw[(k+0)*40+o];
            a1 += h4.y*xpw[(k+1)*40+o];
            a2 += h4.z*xpw[(k+2)*40+o];
            a3 += h4.w*xpw[(k+3)*40+o];
        }
        ssm_s[t][o] = (a0+a1)+(a2+a3);
    }
    __syncthreads();

    #pragma unroll
    for (int e = tid; e < XT*32; e += 256){
        int t = e >> 5, n = e & 31;
        bc[(size_t)(m0+t)*32 + n] = ssm_s[t][8+n];
    }

    {
        const int i = tid;
        float wr[RRs];
        #pragma unroll
        for (int r=0;r<RRs;r++) wr[r] = dtw[r*II + i];
        const float bb = dtb[i];
        #pragma unroll 4
        for (int t=0;t<XT;t++){
            float a = bb;
            #pragma unroll
            for (int r=0;r<RRs;r++) a += ssm_s[t][r]*wr[r];
            dt_out[(size_t)(m0+t)*II + i] = softplusf(a);
        }
    }
}

// ---------------------------------------------------------------------------
// Selective scan, LDS-chunked (unchanged).
// ---------------------------------------------------------------------------
__launch_bounds__(256)
__global__ void scan_kernel(const float* __restrict__ dtp, const float* __restrict__ bc,
                            const float* __restrict__ hconv, const float* __restrict__ hg,
                            const float* __restrict__ A_log, const float* __restrict__ D_par,
                            unsigned short* __restrict__ ybf)
{
    __shared__ float sdt[16][17], shv[16][17], sgv[16][17], sbc[16][33];
    int b = blockIdx.x >> 4, chunk = blockIdx.x & 15;
    int tid = threadIdx.x;
    int n = tid & 15, il = tid >> 4;
    int i = chunk*16 + il;
    float A2 = -__expf(A_log[i*NNs + n]) * 1.44269504f;
    float carry = 0.0f;
    const float dpi = D_par[i];
    const int m0 = b*SQ;
    const int li = tid & 15, ls = tid >> 4;
    const int gi = chunk*16 + li;
    for (int cs=0; cs<16; cs++){
        __syncthreads();
        int mload = m0 + cs*16 + ls;
        sdt[ls][li] = dtp[(size_t)mload*II + gi];
        shv[ls][li] = hconv[(size_t)mload*II + gi];
        sgv[ls][li] = hg[(size_t)mload*(2*II) + II + gi];
        sbc[ls][li]      = bc[(size_t)mload*32 + li];
        sbc[ls][li + 16] = bc[(size_t)mload*32 + 16 + li];
        __syncthreads();
        #pragma unroll
        for (int s=0; s<16; s++){
            float dtv = sdt[s][il];
            float hv  = shv[s][il];
            float dA  = exp2f(dtv*A2);
            carry = carry*dA + dtv*hv*sbc[s][n];
            float acc = carry*sbc[s][16+n];
            acc += __shfl_xor(acc, 1);
            acc += __shfl_xor(acc, 2);
            acc += __shfl_xor(acc, 4);
            acc += __shfl_xor(acc, 8);
            if (n == 0){
                ybf[(size_t)(m0 + cs*16 + s)*II + i] =
                    f2bf((acc + hv*dpi) * siluf(sgv[s][il]));
            }
        }
    }
}

// ---------------------------------------------------------------------------
// Head per batch + KL (unchanged).
// ---------------------------------------------------------------------------
__launch_bounds__(128)
__global__ void head_kernel(const float* __restrict__ x, const float* __restrict__ normf,
                            const float* __restrict__ mu_w, const float* __restrict__ mu_b,
                            const float* __restrict__ lv_w, const float* __restrict__ lv_b,
                            const float* __restrict__ eps, const float* __restrict__ h1_w,
                            const float* __restrict__ h1_b, const float* __restrict__ h2_w,
                            const float* __restrict__ h2_b, float* __restrict__ out,
                            float* __restrict__ klacc)
{
    __shared__ float lasts[DD];
    __shared__ float zs[DD];
    __shared__ float hr[256];
    __shared__ float red[2];
    int b = blockIdx.x, d = threadIdx.x;
    int lane = d & 63, wv = d >> 6;
    float xv = x[((size_t)(b*SQ + SQ-1))*DD + d];
    float ss = xv*xv;
    #pragma unroll
    for (int off=32; off>0; off>>=1) ss += __shfl_xor(ss, off);
    if (lane==0) red[wv] = ss;
    __syncthreads();
    float tot = red[0] + red[1];
    float last = xv * rsqrtf(tot*(1.0f/DD) + 1e-5f) * normf[d];
    lasts[d] = last;
    __syncthreads();
    float mu = mu_b[d], lv = lv_b[d];
    for (int j=0;j<DD;j++){
        float lj = lasts[j];
        mu += lj*mu_w[j*DD + d];
        lv += lj*lv_w[j*DD + d];
    }
    float z = mu + eps[b*ZZs + d]*__expf(0.5f*lv);
    zs[d] = z;
    float klp = 1.0f + lv - mu*mu - __expf(lv);
    #pragma unroll
    for (int off=32; off>0; off>>=1) klp += __shfl_xor(klp, off);
    if (lane==0) red[wv] = klp;
    __syncthreads();
    if (d==0) atomicAdd(klacc, red[0]+red[1]);
    for (int o=d; o<256; o+=128){
        float a = h1_b[o];
        for (int j=0;j<DD;j++) a += zs[j]*h1_w[j*256 + o];
        hr[o] = fmaxf(a, 0.0f);
    }
    __syncthreads();
    if (d < 40){
        float a = h2_b[d];
        for (int k=0;k<256;k++) a += hr[k]*h2_w[k*40 + d];
        out[b*(FUTs*2) + d] = a;
    }
}

__global__ void kl_final_kernel(const float* __restrict__ klacc, float* __restrict__ out)
{
    out[0] = -0.5f * klacc[0] * (1.0f/(BQ*ZZs));
}

// ---------------------------------------------------------------------------
extern "C" void kernel_launch(void* const* d_in, const int* in_sizes, int n_in,
                              void* d_out, int out_size, void* d_ws, size_t ws_size,
                              hipStream_t stream)
{
    const float* x_cam     = (const float*)d_in[0];
    const float* x_ego     = (const float*)d_in[1];
    const float* vib_eps   = (const float*)d_in[2];
    const float* vis_w1    = (const float*)d_in[3];
    const float* vis_b1    = (const float*)d_in[4];
    const float* vis_w2    = (const float*)d_in[5];
    const float* vis_b2    = (const float*)d_in[6];
    const float* ego_w     = (const float*)d_in[7];
    const float* ego_b     = (const float*)d_in[8];
    const float* fus_w     = (const float*)d_in[9];
    const float* fus_b     = (const float*)d_in[10];
    const float* norm_w    = (const float*)d_in[11];
    const float* in_proj_w = (const float*)d_in[12];
    const float* conv_w    = (const float*)d_in[13];
    const float* conv_b    = (const float*)d_in[14];
    const float* x_proj_w  = (const float*)d_in[15];
    const float* dt_proj_w = (const float*)d_in[16];
    const float* dt_proj_b = (const float*)d_in[17];
    const float* A_log     = (const float*)d_in[18];
    const float* D_par     = (const float*)d_in[19];
    const float* out_proj_w= (const float*)d_in[20];
    const float* normf_w   = (const float*)d_in[21];
    const float* mu_w      = (const float*)d_in[22];
    const float* mu_b      = (const float*)d_in[23];
    const float* lv_w      = (const float*)d_in[24];
    const float* lv_b      = (const float*)d_in[25];
    const float* h1_w      = (const float*)d_in[26];
    const float* h1_b      = (const float*)d_in[27];
    const float* h2_w      = (const float*)d_in[28];
    const float* h2_b      = (const float*)d_in[29];

    float* ws = (float*)d_ws;
    float* hg    = ws;                                        // 8192*512 fp32
    unsigned short* v1g  = (unsigned short*)hg;               // 8192*512 bf16 (alias)
    float* hconv = ws + 4194304;                              // 8192*256 fp32
    unsigned short* catbf = (unsigned short*)hconv;           // 8192*256 bf16 (alias)
    float* xbuf  = ws + 6291456;                              // 8192*128
    float* dtws  = ws + 7340032;                              // 8192*256
    float* bcws  = ws + 9437184;                              // 8192*32
    unsigned short* ybf  = (unsigned short*)(ws + 9699328);   // 8192*256 bf16
    unsigned short* xnbf = (unsigned short*)(ws + 10747904);  // 8192*128 bf16
    unsigned short* w1t  = (unsigned short*)(ws + 11272192);  // 512*8192 bf16
    unsigned short* w2t  = (unsigned short*)(ws + 13369344);  // 128*512  bf16
    unsigned short* egot = (unsigned short*)(ws + 13402112);  // 128*64   bf16
    unsigned short* fust = (unsigned short*)(ws + 13406208);  // 128*256  bf16
    unsigned short* wipt = (unsigned short*)(ws + 13422592);  // 4*512*128 bf16
    unsigned short* wopt = (unsigned short*)(ws + 13553664);  // 4*128*256 bf16
    float* klacc = ws + 13619200;
    unsigned short* xcbf = (unsigned short*)(ws + 13619208);  // 8192*8192 bf16
    const size_t need_bytes = (size_t)(13619208 + 33554432) * 4;
    const bool big_ws = (ws_size >= need_bytes);

    hipMemsetAsync(klacc, 0, sizeof(float), stream);

    // ---- weight casts: bf16 + transpose to [N][K] ----
    castT_kernel<<<dim3(8, 128), 256, 0, stream>>>(vis_w1, w1t, 8192, 512);
    castT_kernel<<<dim3(2, 8),   256, 0, stream>>>(vis_w2, w2t, 512, 128);
    castT_kernel<<<dim3(2, 1),   256, 0, stream>>>(ego_w,  egot, 64, 128);
    castT_kernel<<<dim3(2, 4),   256, 0, stream>>>(fus_w,  fust, 256, 128);
    for (int l=0; l<LLs; l++){
        castT_kernel<<<dim3(8, 2), 256, 0, stream>>>(
            in_proj_w + (size_t)l*DD*2*II, wipt + (size_t)l*2*II*DD, DD, 2*II);
        castT_kernel<<<dim3(2, 4), 256, 0, stream>>>(
            out_proj_w + (size_t)l*II*DD, wopt + (size_t)l*DD*II, II, DD);
    }

    // 1) vision GEMM1: gelu(x_cam @ W1 + b1) -> v1g (bf16 out)
    if (big_ws){
        cast_bf16_kernel<<<32768, 256, 0, stream>>>(x_cam, xcbf);   // 67M elems
        gemm_w512_kernel<1,0,1><<<dim3(64, 4), 512, 0, stream>>>(
            xcbf, w1t, vis_b1, v1g, MTOK, 512, 8192, 512);
    } else {
        gemm_bf16_kernel<1,0,1,float><<<dim3(64, 8), 256, 0, stream>>>(
            x_cam, w1t, vis_b1, v1g, MTOK, 512, 8192, 512);
    }
    // 2) v2 = v1g @ W2 + b2 -> catbf[:, :128] (bf16 out)
    gemm_lds64_kernel<0,0,1><<<dim3(128, 2), 256, 0, stream>>>(
        v1g, w2t, vis_b2, catbf, MTOK, 128, 512, 256);
    // 3) e = x_ego @ ego_w + b -> catbf[:, 128:]  (fp32 A, K=64 -> legacy)
    gemm_bf16_kernel<0,0,1,float><<<dim3(64, 2), 256, 0, stream>>>(
        x_ego, egot, ego_b, catbf + 128, MTOK, 128, 64, 256);
    // 4) fused = gelu(catbf @ fus_w + b) -> xbuf (fp32 residual stream)
    gemm_lds64_kernel<1,0,0><<<dim3(128, 2), 256, 0, stream>>>(
        catbf, fust, fus_b, xbuf, MTOK, 128, 256, 128);

    for (int l=0; l<LLs; l++){
        rms_bf_kernel<<<MTOK/4, 256, 0, stream>>>(xbuf, norm_w + l*DD, xnbf);
        gemm_w512_kernel<0,0,0><<<dim3(64, 4), 512, 0, stream>>>(
            xnbf, wipt + (size_t)l*2*II*DD, nullptr, hg, MTOK, 2*II, DD, 2*II);
        conv_kernel<<<MTOK*II/256, 256, 0, stream>>>(
            hg, conv_w + (size_t)l*II*KKs, conv_b + (size_t)l*II, hconv);
        xproj_fused_kernel<<<MTOK/XT, 256, 0, stream>>>(
            hconv, x_proj_w + (size_t)l*II*40, dt_proj_w + (size_t)l*RRs*II,
            dt_proj_b + (size_t)l*II, dtws, bcws);
        scan_kernel<<<BQ*16, 256, 0, stream>>>(
            dtws, bcws, hconv, hg, A_log + (size_t)l*II*NNs, D_par + (size_t)l*II, ybf);
        gemm_lds64_kernel<0,1,0><<<dim3(128, 2), 256, 0, stream>>>(
            ybf, wopt + (size_t)l*DD*II, nullptr, xbuf, MTOK, DD, II, DD);
    }

    head_kernel<<<BQ, 128, 0, stream>>>(
        xbuf, normf_w, mu_w, mu_b, lv_w, lv_b, vib_eps,
        h1_w, h1_b, h2_w, h2_b, (float*)d_out, klacc);
    kl_final_kernel<<<1, 1, 0, stream>>>(klacc, (float*)d_out + 1280);
}

// Round 6
// 1172.748 us; speedup vs baseline: 1.0662x; 1.0469x over previous
//
#include <hip/hip_runtime.h>
#include <hip/hip_bf16.h>
#include <math.h>

#define BQ 32
#define SQ 256
#define MTOK 8192       // B*S
#define DD 128
#define II 256
#define NNs 16
#define RRs 8
#define KKs 4
#define LLs 4
#define ZZs 128
#define FUTs 20

typedef __attribute__((ext_vector_type(8))) short bf8v;   // 8 bf16 (4 VGPRs)
typedef __attribute__((ext_vector_type(4))) float f4v;    // 4 fp32 acc

__device__ __forceinline__ float geluf(float x){ return 0.5f*x*(1.0f+erff(x*0.70710678118654752f)); }
__device__ __forceinline__ float siluf(float x){ return x/(1.0f+__expf(-x)); }
__device__ __forceinline__ float softplusf(float x){ return fmaxf(x,0.0f)+log1pf(__expf(-fabsf(x))); }
__device__ __forceinline__ unsigned short f2bf(float x){
    __hip_bfloat16 h = __float2bfloat16(x);
    return *reinterpret_cast<unsigned short*>(&h);
}

// async global -> LDS, 16B per lane. LDS dest is wave-uniform base + lane*16.
__device__ __forceinline__ void gload_lds16(const void* g, void* l){
    __builtin_amdgcn_global_load_lds(
        (const __attribute__((address_space(1))) void*)g,
        (__attribute__((address_space(3))) void*)l, 16, 0, 0);
}

// counted-vmcnt wait + workgroup barrier (kept for gemm_w512 / gemm_lds64).
#define PIPE_WAIT_BAR(N) do {                                   \
    __builtin_amdgcn_sched_barrier(0);                          \
    asm volatile("s_waitcnt vmcnt(" #N ")" ::: "memory");       \
    __builtin_amdgcn_s_barrier();                               \
    __builtin_amdgcn_sched_barrier(0);                          \
} while(0)

#define PIPE_END_BAR() do {                                     \
    __builtin_amdgcn_sched_barrier(0);                          \
    asm volatile("s_waitcnt lgkmcnt(0)" ::: "memory");          \
    __builtin_amdgcn_s_barrier();                               \
    __builtin_amdgcn_sched_barrier(0);                          \
} while(0)

// ---------------------------------------------------------------------------
// fp32-A bf16 GEMM (GEMM1): BM=BN=128, BK=64, 512 threads (8 waves, 2Mx4N),
// acc[4][2]. A is fp32 and converted IN-STAGING: per thread 2x(2xfloat4
// loads -> 8x f2bf -> 1x swizzled ds_write_b128). B (bf16) via gload_lds
// with pre-swizzled source. Eliminates the standalone 65us cast kernel +
// xcbf round-trip (R5 post-mortem: traffic/pipeline levers are neutral at
// this size -- the cast was pure overhead). Double LDS buffer, ONE
// __syncthreads per K-step (its vmcnt/lgkm drain covers A-regs, B-gload,
// and ds_write visibility; counted-vmcnt proven neutral in R3).
// Same XOR swizzle as R2 (conflicts=0); same MFMA order as R5 -> output
// bit-identical. Requires Kd%64==0, Kd>=128. Grid (M/128, N/128).
// ---------------------------------------------------------------------------
template<int ACT,int OUTBF>
__launch_bounds__(512,1)
__global__ void gemm_f32a_kernel(const float* __restrict__ A,
                                 const unsigned short* __restrict__ Bt,
                                 const float* __restrict__ bias,
                                 void* __restrict__ Cv,
                                 int M, int N, int Kd, int ldc)
{
    __shared__ __align__(16) unsigned short As[2][128*64];
    __shared__ __align__(16) unsigned short Bs[2][128*64];
    const int tid = threadIdx.x;
    const int w = tid >> 6, lane = tid & 63;
    const int ml = lane & 15, quad = lane >> 4;
    const int wm = w >> 2, wn = w & 3;            // 2M x 4N wave grid
    const int rowBase = blockIdx.x * 128, colBase = blockIdx.y * 128;

    // A staging mapping: thread covers (row = arow + c*64, slot = aslot)
    const int arow  = tid >> 3;                   // 0..63
    const int aslot = tid & 7;                    // 0..7 (16B slots)
    const int awslot = aslot ^ (arow & 7);        // swizzled LDS slot

    // B staging mapping (gload_lds): chunk c = w*2+e, row c*8+(lane>>3)
    const int srow = lane >> 3;
    const int scol = (((lane&7) ^ (lane>>3)))*8;  // pre-swizzled global col

    f4v acc[4][2];
    #pragma unroll
    for (int i=0;i<4;i++)
      #pragma unroll
      for (int j=0;j<2;j++) acc[i][j] = (f4v){0.f,0.f,0.f,0.f};

    float4 pa[2][2];
    auto loadA = [&](int kt){
        #pragma unroll
        for (int c=0;c<2;c++){
            const float* ap = A + (size_t)(rowBase + arow + c*64)*Kd + kt + aslot*8;
            pa[c][0] = *reinterpret_cast<const float4*>(ap);
            pa[c][1] = *reinterpret_cast<const float4*>(ap+4);
        }
    };
    auto writeA = [&](int buf){
        #pragma unroll
        for (int c=0;c<2;c++){
            union { unsigned short u[8]; bf8v v; } o;
            o.u[0]=f2bf(pa[c][0].x); o.u[1]=f2bf(pa[c][0].y);
            o.u[2]=f2bf(pa[c][0].z); o.u[3]=f2bf(pa[c][0].w);
            o.u[4]=f2bf(pa[c][1].x); o.u[5]=f2bf(pa[c][1].y);
            o.u[6]=f2bf(pa[c][1].z); o.u[7]=f2bf(pa[c][1].w);
            *reinterpret_cast<bf8v*>(&As[buf][(arow + c*64)*64 + awslot*8]) = o.v;
        }
    };
    auto stageB = [&](int buf, int kt){
        #pragma unroll
        for (int e=0;e<2;e++){
            const int c = w*2 + e;                // chunk 0..15 (8 rows each)
            const unsigned short* src = Bt + (size_t)(colBase + c*8 + srow)*Kd + kt + scol;
            gload_lds16(src, (unsigned short*)Bs[buf] + c*512);
        }
    };

    const int swz = (ml&7)*8;                     // read-side XOR (elems)
    auto compute = [&](int buf){
        #pragma unroll
        for (int ks=0; ks<2; ks++){
            const int co = (ks*32 + quad*8) ^ swz;
            bf8v a[4], b[2];
            #pragma unroll
            for (int mf=0; mf<4; mf++)
                a[mf] = *reinterpret_cast<const bf8v*>(&As[buf][(wm*64 + mf*16 + ml)*64 + co]);
            #pragma unroll
            for (int nf=0; nf<2; nf++)
                b[nf] = *reinterpret_cast<const bf8v*>(&Bs[buf][(wn*32 + nf*16 + ml)*64 + co]);
            #pragma unroll
            for (int mf=0; mf<4; mf++)
                #pragma unroll
                for (int nf=0; nf<2; nf++)
                    acc[mf][nf] = __builtin_amdgcn_mfma_f32_16x16x32_bf16(a[mf], b[nf], acc[mf][nf], 0,0,0);
        }
    };

    // prologue: tile 0 into buf 0
    loadA(0);
    stageB(0, 0);
    writeA(0);                 // compiler waits the float4 regs
    __syncthreads();           // drains vmcnt (B gload) + lgkm (ds_write)

    int buf = 0;
    for (int kt=0; kt<Kd; kt+=64){
        const bool more = (kt + 64 < Kd);
        if (more){ loadA(kt+64); stageB(buf^1, kt+64); }   // fly during MFMA
        compute(buf);
        if (more) writeA(buf^1);                           // after A-regs land
        __syncthreads();       // B landed + A written + all reads of buf done
        buf ^= 1;
    }

    #pragma unroll
    for (int mf=0; mf<4; mf++){
        #pragma unroll
        for (int nf=0; nf<2; nf++){
            int col = colBase + wn*32 + nf*16 + ml;
            float bb = bias ? bias[col] : 0.0f;
            #pragma unroll
            for (int r=0;r<4;r++){
                int row = rowBase + wm*64 + mf*16 + quad*4 + r;
                float v = acc[mf][nf][r] + bb;
                if (ACT==1) v = geluf(v);
                if constexpr (OUTBF==1){
                    ((unsigned short*)Cv)[(size_t)row*ldc + col] = f2bf(v);
                } else {
                    float* cp = (float*)Cv + (size_t)row*ldc + col;
                    *cp = v;
                }
            }
        }
    }
}

// ---------------------------------------------------------------------------
// 512-thread bf16 GEMM (in_proj): BM=BN=128, BK=64, 8 waves (2M x 4N).
// 3-buffer counted-vmcnt ring, XOR swizzle. Grid (M/128, N/128).
// ---------------------------------------------------------------------------
template<int ACT,int ADD,int OUTBF>
__launch_bounds__(512,1)
__global__ void gemm_w512_kernel(const unsigned short* __restrict__ A,
                                 const unsigned short* __restrict__ Bt,
                                 const float* __restrict__ bias,
                                 void* __restrict__ Cv,
                                 int M, int N, int Kd, int ldc)
{
    __shared__ __align__(16) unsigned short As[3][128*64];
    __shared__ __align__(16) unsigned short Bs[3][128*64];
    const int tid = threadIdx.x;
    const int w = tid >> 6, lane = tid & 63;
    const int ml = lane & 15, quad = lane >> 4;
    const int wm = w >> 2, wn = w & 3;
    const int rowBase = blockIdx.x * 128, colBase = blockIdx.y * 128;

    const int srow = lane >> 3;
    const int scol = (((lane&7) ^ (lane>>3)))*8;

    f4v acc[4][2];
    #pragma unroll
    for (int i=0;i<4;i++)
      #pragma unroll
      for (int j=0;j<2;j++) acc[i][j] = (f4v){0.f,0.f,0.f,0.f};

    auto stage = [&](int buf, int kt){
        #pragma unroll
        for (int e=0;e<2;e++){
            const int c = w*2 + e;
            const unsigned short* srcA = A + (size_t)(rowBase + c*8 + srow)*Kd + kt + scol;
            gload_lds16(srcA, (unsigned short*)As[buf] + c*512);
            const unsigned short* srcB = Bt + (size_t)(colBase + c*8 + srow)*Kd + kt + scol;
            gload_lds16(srcB, (unsigned short*)Bs[buf] + c*512);
        }
    };

    const int swz = (ml&7)*8;

    auto compute = [&](int buf){
        #pragma unroll
        for (int ks=0; ks<2; ks++){
            const int co = (ks*32 + quad*8) ^ swz;
            bf8v a[4], b[2];
            #pragma unroll
            for (int mf=0; mf<4; mf++)
                a[mf] = *reinterpret_cast<const bf8v*>(&As[buf][(wm*64 + mf*16 + ml)*64 + co]);
            #pragma unroll
            for (int nf=0; nf<2; nf++)
                b[nf] = *reinterpret_cast<const bf8v*>(&Bs[buf][(wn*32 + nf*16 + ml)*64 + co]);
            #pragma unroll
            for (int mf=0; mf<4; mf++)
                #pragma unroll
                for (int nf=0; nf<2; nf++)
                    acc[mf][nf] = __builtin_amdgcn_mfma_f32_16x16x32_bf16(a[mf], b[nf], acc[mf][nf], 0,0,0);
        }
    };

    const int nIter = Kd >> 6;
    stage(0, 0);
    stage(1, 64);

    int i = 0;
    for (; i + 2 < nIter; ++i){
        stage((i+2)%3, (i+2)<<6);
        PIPE_WAIT_BAR(8);
        compute(i%3);
        PIPE_END_BAR();
    }
    PIPE_WAIT_BAR(4);
    compute(i%3);
    PIPE_END_BAR();
    ++i;
    PIPE_WAIT_BAR(0);
    compute(i%3);

    #pragma unroll
    for (int mf=0; mf<4; mf++){
        #pragma unroll
        for (int nf=0; nf<2; nf++){
            int col = colBase + wn*32 + nf*16 + ml;
            float bb = bias ? bias[col] : 0.0f;
            #pragma unroll
            for (int r=0;r<4;r++){
                int row = rowBase + wm*64 + mf*16 + quad*4 + r;
                float v = acc[mf][nf][r] + bb;
                if (ACT==1) v = geluf(v);
                if constexpr (OUTBF==1){
                    ((unsigned short*)Cv)[(size_t)row*ldc + col] = f2bf(v);
                } else {
                    float* cp = (float*)Cv + (size_t)row*ldc + col;
                    if (ADD) v += *cp;
                    *cp = v;
                }
            }
        }
    }
}

// ---------------------------------------------------------------------------
// BM=BN=64 bf16 GEMM for N=128 outputs: grid (M/64, N/64) = 256 blocks ->
// full CU coverage. 3-buffer counted-vmcnt ring (48KB LDS), XOR swizzle.
// ---------------------------------------------------------------------------
template<int ACT,int ADD,int OUTBF>
__launch_bounds__(256,2)
__global__ void gemm_lds64_kernel(const unsigned short* __restrict__ A,
                                  const unsigned short* __restrict__ Bt,
                                  const float* __restrict__ bias,
                                  void* __restrict__ Cv,
                                  int M, int N, int Kd, int ldc)
{
    __shared__ __align__(16) unsigned short As[3][64*64];
    __shared__ __align__(16) unsigned short Bs[3][64*64];
    const int tid = threadIdx.x;
    const int w = tid >> 6, lane = tid & 63;
    const int ml = lane & 15, quad = lane >> 4;
    const int rowBase = blockIdx.x * 64, colBase = blockIdx.y * 64;

    const int srow = lane >> 3;
    const int scol = (((lane&7) ^ (lane>>3)))*8;

    f4v acc[4];
    #pragma unroll
    for (int j=0;j<4;j++) acc[j] = (f4v){0.f,0.f,0.f,0.f};

    auto stage = [&](int buf, int kt){
        #pragma unroll
        for (int e=0;e<2;e++){
            const int c = w*2 + e;
            const unsigned short* srcA = A + (size_t)(rowBase + c*8 + srow)*Kd + kt + scol;
            gload_lds16(srcA, (unsigned short*)As[buf] + c*512);
            const unsigned short* srcB = Bt + (size_t)(colBase + c*8 + srow)*Kd + kt + scol;
            gload_lds16(srcB, (unsigned short*)Bs[buf] + c*512);
        }
    };

    const int swz = (ml&7)*8;

    auto compute = [&](int buf){
        #pragma unroll
        for (int ks=0; ks<2; ks++){
            const int co = (ks*32 + quad*8) ^ swz;
            bf8v a0 = *reinterpret_cast<const bf8v*>(&As[buf][(w*16 + ml)*64 + co]);
            #pragma unroll
            for (int nt=0; nt<4; nt++){
                bf8v b = *reinterpret_cast<const bf8v*>(&Bs[buf][(nt*16+ml)*64 + co]);
                acc[nt] = __builtin_amdgcn_mfma_f32_16x16x32_bf16(a0, b, acc[nt], 0,0,0);
            }
        }
    };

    const int nIter = Kd >> 6;
    stage(0, 0);
    stage(1, 64);

    int i = 0;
    for (; i + 2 < nIter; ++i){
        stage((i+2)%3, (i+2)<<6);
        PIPE_WAIT_BAR(8);
        compute(i%3);
        PIPE_END_BAR();
    }
    PIPE_WAIT_BAR(4);
    compute(i%3);
    PIPE_END_BAR();
    ++i;
    PIPE_WAIT_BAR(0);
    compute(i%3);

    #pragma unroll
    for (int nt=0; nt<4; nt++){
        int col = colBase + nt*16 + ml;
        float bb = bias ? bias[col] : 0.0f;
        #pragma unroll
        for (int r=0;r<4;r++){
            int row = rowBase + w*16 + quad*4 + r;
            float v = acc[nt][r] + bb;
            if (ACT==1) v = geluf(v);
            if constexpr (OUTBF==1){
                ((unsigned short*)Cv)[(size_t)row*ldc + col] = f2bf(v);
            } else {
                float* cp = (float*)Cv + (size_t)row*ldc + col;
                if (ADD) v += *cp;
                *cp = v;
            }
        }
    }
}

// ---------------------------------------------------------------------------
// Legacy reg-staged GEMM (fp32 A). Kept for GEMM3 (x_ego, K=64).
// ---------------------------------------------------------------------------
template<int ACT,int ADD,int OUTBF,typename AT>
__launch_bounds__(256,2)
__global__ void gemm_bf16_kernel(const AT* __restrict__ A,
                                 const unsigned short* __restrict__ Bt,
                                 const float* __restrict__ bias,
                                 void* __restrict__ Cv,
                                 int M, int N, int Kd, int ldc)
{
    constexpr int LDK = 72;
    __shared__ unsigned short As[128*LDK];
    __shared__ unsigned short Bs[64*LDK];
    const int tid = threadIdx.x;
    const int w = tid >> 6, lane = tid & 63;
    const int ml = lane & 15, quad = lane >> 4;
    const int rowBase = blockIdx.x * 128, colBase = blockIdx.y * 64;

    f4v acc[2][4];
    #pragma unroll
    for (int i=0;i<2;i++)
      #pragma unroll
      for (int j=0;j<4;j++) acc[i][j] = (f4v){0.f,0.f,0.f,0.f};

    bf8v pa[4], pb[2];
    const int ar = tid >> 3, as8 = (tid & 7) * 8;

    auto loadTile = [&](int kt){
        #pragma unroll
        for (int e=0;e<4;e++){
            int r = ar + e*32;
            if constexpr (sizeof(AT)==2){
                pa[e] = *reinterpret_cast<const bf8v*>(
                    (const unsigned short*)A + (size_t)(rowBase+r)*Kd + kt + as8);
            } else {
                const float* ap = (const float*)A + (size_t)(rowBase+r)*Kd + kt + as8;
                float4 v0 = *reinterpret_cast<const float4*>(ap);
                float4 v1 = *reinterpret_cast<const float4*>(ap+4);
                union { unsigned short u[8]; bf8v v; } o;
                o.u[0]=f2bf(v0.x); o.u[1]=f2bf(v0.y); o.u[2]=f2bf(v0.z); o.u[3]=f2bf(v0.w);
                o.u[4]=f2bf(v1.x); o.u[5]=f2bf(v1.y); o.u[6]=f2bf(v1.z); o.u[7]=f2bf(v1.w);
                pa[e] = o.v;
            }
        }
        #pragma unroll
        for (int e=0;e<2;e++){
            int r = ar + e*32;
            pb[e] = *reinterpret_cast<const bf8v*>(
                Bt + (size_t)(colBase+r)*Kd + kt + as8);
        }
    };

    loadTile(0);

    for (int kt=0; kt<Kd; kt+=64){
        #pragma unroll
        for (int e=0;e<4;e++) *reinterpret_cast<bf8v*>(&As[(ar+e*32)*LDK + as8]) = pa[e];
        #pragma unroll
        for (int e=0;e<2;e++) *reinterpret_cast<bf8v*>(&Bs[(ar+e*32)*LDK + as8]) = pb[e];
        __syncthreads();
        if (kt + 64 < Kd) loadTile(kt + 64);
        #pragma unroll
        for (int ks=0; ks<2; ks++){
            bf8v a0 = *reinterpret_cast<bf8v*>(&As[(w*32 +      ml)*LDK + ks*32 + quad*8]);
            bf8v a1 = *reinterpret_cast<bf8v*>(&As[(w*32 + 16 + ml)*LDK + ks*32 + quad*8]);
            #pragma unroll
            for (int nt=0; nt<4; nt++){
                bf8v b = *reinterpret_cast<bf8v*>(&Bs[(nt*16+ml)*LDK + ks*32 + quad*8]);
                acc[0][nt] = __builtin_amdgcn_mfma_f32_16x16x32_bf16(a0, b, acc[0][nt], 0,0,0);
                acc[1][nt] = __builtin_amdgcn_mfma_f32_16x16x32_bf16(a1, b, acc[1][nt], 0,0,0);
            }
        }
        __syncthreads();
    }

    #pragma unroll
    for (int mt=0; mt<2; mt++){
        #pragma unroll
        for (int nt=0; nt<4; nt++){
            int col = colBase + nt*16 + ml;
            float bb = bias ? bias[col] : 0.0f;
            #pragma unroll
            for (int r=0;r<4;r++){
                int row = rowBase + w*32 + mt*16 + quad*4 + r;
                float v = acc[mt][nt][r] + bb;
                if (ACT==1) v = geluf(v);
                if constexpr (OUTBF==1){
                    ((unsigned short*)Cv)[(size_t)row*ldc + col] = f2bf(v);
                } else {
                    float* cp = (float*)Cv + (size_t)row*ldc + col;
                    if (ADD) v += *cp;
                    *cp = v;
                }
            }
        }
    }
}

// ---------------------------------------------------------------------------
// fp32 [K][N] -> bf16 [N][K] cast + transpose, 64x64 LDS tiles.
// ---------------------------------------------------------------------------
__launch_bounds__(256)
__global__ void castT_kernel(const float* __restrict__ in, unsigned short* __restrict__ out,
                             int Kd, int N)
{
    __shared__ float t[64][65];
    int k0 = blockIdx.y*64, n0 = blockIdx.x*64;
    int c = threadIdx.x & 63, r4 = threadIdx.x >> 6;
    #pragma unroll
    for (int it=0; it<16; it++){
        int row = it*4 + r4;
        t[row][c] = in[(size_t)(k0+row)*N + n0 + c];
    }
    __syncthreads();
    #pragma unroll
    for (int it=0; it<16; it++){
        int row = it*4 + r4;
        out[(size_t)(n0+row)*Kd + k0 + c] = f2bf(t[c][row]);
    }
}

// ---------------------------------------------------------------------------
// RMSNorm -> bf16 out: one wave per token
// ---------------------------------------------------------------------------
__launch_bounds__(256)
__global__ void rms_bf_kernel(const float* __restrict__ x, const float* __restrict__ w,
                              unsigned short* __restrict__ out)
{
    int tid = threadIdx.x;
    int lane = tid & 63, wv = tid >> 6;
    int token = blockIdx.x*4 + wv;
    const float* xr = x + (size_t)token*DD;
    float v0 = xr[lane], v1 = xr[lane+64];
    float ss = v0*v0 + v1*v1;
    #pragma unroll
    for (int off=32; off>0; off>>=1) ss += __shfl_xor(ss, off);
    float r = rsqrtf(ss*(1.0f/DD) + 1e-5f);
    unsigned short* o = out + (size_t)token*DD;
    o[lane]    = f2bf(v0*r*w[lane]);
    o[lane+64] = f2bf(v1*r*w[lane+64]);
}

// ---------------------------------------------------------------------------
// Depthwise causal conv (K=4) + bias + silu.
// ---------------------------------------------------------------------------
__launch_bounds__(256)
__global__ void conv_kernel(const float* __restrict__ hg, const float* __restrict__ cw,
                            const float* __restrict__ cb, float* __restrict__ hc)
{
    int idx = blockIdx.x*256 + threadIdx.x;
    int i = idx & (II-1);
    int m = idx >> 8;
    int s = m & (SQ-1);
    const float* w = cw + i*KKs;
    float a = cb[i];
    #pragma unroll
    for (int k=0;k<KKs;k++){
        int ssrc = s + k - (KKs-1);
        if (ssrc >= 0) a += hg[(size_t)(m + k - (KKs-1))*(2*II) + i] * w[k];
    }
    hc[idx] = siluf(a);
}

// ---------------------------------------------------------------------------
// Fused x_proj + dt_proj + softplus + B/C extraction. fp32 throughout.
// ---------------------------------------------------------------------------
#define XT 16
__launch_bounds__(256)
__global__ void xproj_fused_kernel(const float* __restrict__ hconv,
                                   const float* __restrict__ xpw,
                                   const float* __restrict__ dtw,
                                   const float* __restrict__ dtb,
                                   float* __restrict__ dt_out,
                                   float* __restrict__ bc)
{
    __shared__ float sh[XT][II+4];
    __shared__ float ssm_s[XT][40];
    const int tid = threadIdx.x;
    const int m0 = blockIdx.x * XT;

    {
        const float4* src = reinterpret_cast<const float4*>(hconv + (size_t)m0*II);
        #pragma unroll
        for (int e=0;e<4;e++){
            int idx = e*256 + tid;
            int t = idx >> 6, c = idx & 63;
            *reinterpret_cast<float4*>(&sh[t][c*4]) = src[idx];
        }
    }
    __syncthreads();

    for (int e = tid; e < XT*40; e += 256){
        int t = e / 40, o = e - t*40;
        float a0=0.f, a1=0.f, a2=0.f, a3=0.f;
        #pragma unroll 16
        for (int k=0;k<II;k+=4){
            float4 h4 = *reinterpret_cast<const float4*>(&sh[t][k]);
            a0 += h4.x*xpw[(k+0)*40+o];
            a1 += h4.y*xpw[(k+1)*40+o];
            a2 += h4.z*xpw[(k+2)*40+o];
            a3 += h4.w*xpw[(k+3)*40+o];
        }
        ssm_s[t][o] = (a0+a1)+(a2+a3);
    }
    __syncthreads();

    #pragma unroll
    for (int e = tid; e < XT*32; e += 256){
        int t = e >> 5, n = e & 31;
        bc[(size_t)(m0+t)*32 + n] = ssm_s[t][8+n];
    }

    {
        const int i = tid;
        float wr[RRs];
        #pragma unroll
        for (int r=0;r<RRs;r++) wr[r] = dtw[r*II + i];
        const float bb = dtb[i];
        #pragma unroll 4
        for (int t=0;t<XT;t++){
            float a = bb;
            #pragma unroll
            for (int r=0;r<RRs;r++) a += ssm_s[t][r]*wr[r];
            dt_out[(size_t)(m0+t)*II + i] = softplusf(a);
        }
    }
}

// ---------------------------------------------------------------------------
// Selective scan, LDS-chunked (unchanged).
// ---------------------------------------------------------------------------
__launch_bounds__(256)
__global__ void scan_kernel(const float* __restrict__ dtp, const float* __restrict__ bc,
                            const float* __restrict__ hconv, const float* __restrict__ hg,
                            const float* __restrict__ A_log, const float* __restrict__ D_par,
                            unsigned short* __restrict__ ybf)
{
    __shared__ float sdt[16][17], shv[16][17], sgv[16][17], sbc[16][33];
    int b = blockIdx.x >> 4, chunk = blockIdx.x & 15;
    int tid = threadIdx.x;
    int n = tid & 15, il = tid >> 4;
    int i = chunk*16 + il;
    float A2 = -__expf(A_log[i*NNs + n]) * 1.44269504f;
    float carry = 0.0f;
    const float dpi = D_par[i];
    const int m0 = b*SQ;
    const int li = tid & 15, ls = tid >> 4;
    const int gi = chunk*16 + li;
    for (int cs=0; cs<16; cs++){
        __syncthreads();
        int mload = m0 + cs*16 + ls;
        sdt[ls][li] = dtp[(size_t)mload*II + gi];
        shv[ls][li] = hconv[(size_t)mload*II + gi];
        sgv[ls][li] = hg[(size_t)mload*(2*II) + II + gi];
        sbc[ls][li]      = bc[(size_t)mload*32 + li];
        sbc[ls][li + 16] = bc[(size_t)mload*32 + 16 + li];
        __syncthreads();
        #pragma unroll
        for (int s=0; s<16; s++){
            float dtv = sdt[s][il];
            float hv  = shv[s][il];
            float dA  = exp2f(dtv*A2);
            carry = carry*dA + dtv*hv*sbc[s][n];
            float acc = carry*sbc[s][16+n];
            acc += __shfl_xor(acc, 1);
            acc += __shfl_xor(acc, 2);
            acc += __shfl_xor(acc, 4);
            acc += __shfl_xor(acc, 8);
            if (n == 0){
                ybf[(size_t)(m0 + cs*16 + s)*II + i] =
                    f2bf((acc + hv*dpi) * siluf(sgv[s][il]));
            }
        }
    }
}

// ---------------------------------------------------------------------------
// Head per batch + KL (unchanged).
// ---------------------------------------------------------------------------
__launch_bounds__(128)
__global__ void head_kernel(const float* __restrict__ x, const float* __restrict__ normf,
                            const float* __restrict__ mu_w, const float* __restrict__ mu_b,
                            const float* __restrict__ lv_w, const float* __restrict__ lv_b,
                            const float* __restrict__ eps, const float* __restrict__ h1_w,
                            const float* __restrict__ h1_b, const float* __restrict__ h2_w,
                            const float* __restrict__ h2_b, float* __restrict__ out,
                            float* __restrict__ klacc)
{
    __shared__ float lasts[DD];
    __shared__ float zs[DD];
    __shared__ float hr[256];
    __shared__ float red[2];
    int b = blockIdx.x, d = threadIdx.x;
    int lane = d & 63, wv = d >> 6;
    float xv = x[((size_t)(b*SQ + SQ-1))*DD + d];
    float ss = xv*xv;
    #pragma unroll
    for (int off=32; off>0; off>>=1) ss += __shfl_xor(ss, off);
    if (lane==0) red[wv] = ss;
    __syncthreads();
    float tot = red[0] + red[1];
    float last = xv * rsqrtf(tot*(1.0f/DD) + 1e-5f) * normf[d];
    lasts[d] = last;
    __syncthreads();
    float mu = mu_b[d], lv = lv_b[d];
    for (int j=0;j<DD;j++){
        float lj = lasts[j];
        mu += lj*mu_w[j*DD + d];
        lv += lj*lv_w[j*DD + d];
    }
    float z = mu + eps[b*ZZs + d]*__expf(0.5f*lv);
    zs[d] = z;
    float klp = 1.0f + lv - mu*mu - __expf(lv);
    #pragma unroll
    for (int off=32; off>0; off>>=1) klp += __shfl_xor(klp, off);
    if (lane==0) red[wv] = klp;
    __syncthreads();
    if (d==0) atomicAdd(klacc, red[0]+red[1]);
    for (int o=d; o<256; o+=128){
        float a = h1_b[o];
        for (int j=0;j<DD;j++) a += zs[j]*h1_w[j*256 + o];
        hr[o] = fmaxf(a, 0.0f);
    }
    __syncthreads();
    if (d < 40){
        float a = h2_b[d];
        for (int k=0;k<256;k++) a += hr[k]*h2_w[k*40 + d];
        out[b*(FUTs*2) + d] = a;
    }
}

__global__ void kl_final_kernel(const float* __restrict__ klacc, float* __restrict__ out)
{
    out[0] = -0.5f * klacc[0] * (1.0f/(BQ*ZZs));
}

// ---------------------------------------------------------------------------
extern "C" void kernel_launch(void* const* d_in, const int* in_sizes, int n_in,
                              void* d_out, int out_size, void* d_ws, size_t ws_size,
                              hipStream_t stream)
{
    const float* x_cam     = (const float*)d_in[0];
    const float* x_ego     = (const float*)d_in[1];
    const float* vib_eps   = (const float*)d_in[2];
    const float* vis_w1    = (const float*)d_in[3];
    const float* vis_b1    = (const float*)d_in[4];
    const float* vis_w2    = (const float*)d_in[5];
    const float* vis_b2    = (const float*)d_in[6];
    const float* ego_w     = (const float*)d_in[7];
    const float* ego_b     = (const float*)d_in[8];
    const float* fus_w     = (const float*)d_in[9];
    const float* fus_b     = (const float*)d_in[10];
    const float* norm_w    = (const float*)d_in[11];
    const float* in_proj_w = (const float*)d_in[12];
    const float* conv_w    = (const float*)d_in[13];
    const float* conv_b    = (const float*)d_in[14];
    const float* x_proj_w  = (const float*)d_in[15];
    const float* dt_proj_w = (const float*)d_in[16];
    const float* dt_proj_b = (const float*)d_in[17];
    const float* A_log     = (const float*)d_in[18];
    const float* D_par     = (const float*)d_in[19];
    const float* out_proj_w= (const float*)d_in[20];
    const float* normf_w   = (const float*)d_in[21];
    const float* mu_w      = (const float*)d_in[22];
    const float* mu_b      = (const float*)d_in[23];
    const float* lv_w      = (const float*)d_in[24];
    const float* lv_b      = (const float*)d_in[25];
    const float* h1_w      = (const float*)d_in[26];
    const float* h1_b      = (const float*)d_in[27];
    const float* h2_w      = (const float*)d_in[28];
    const float* h2_b      = (const float*)d_in[29];

    float* ws = (float*)d_ws;
    float* hg    = ws;                                        // 8192*512 fp32
    unsigned short* v1g  = (unsigned short*)hg;               // 8192*512 bf16 (alias)
    float* hconv = ws + 4194304;                              // 8192*256 fp32
    unsigned short* catbf = (unsigned short*)hconv;           // 8192*256 bf16 (alias)
    float* xbuf  = ws + 6291456;                              // 8192*128
    float* dtws  = ws + 7340032;                              // 8192*256
    float* bcws  = ws + 9437184;                              // 8192*32
    unsigned short* ybf  = (unsigned short*)(ws + 9699328);   // 8192*256 bf16
    unsigned short* xnbf = (unsigned short*)(ws + 10747904);  // 8192*128 bf16
    unsigned short* w1t  = (unsigned short*)(ws + 11272192);  // 512*8192 bf16
    unsigned short* w2t  = (unsigned short*)(ws + 13369344);  // 128*512  bf16
    unsigned short* egot = (unsigned short*)(ws + 13402112);  // 128*64   bf16
    unsigned short* fust = (unsigned short*)(ws + 13406208);  // 128*256  bf16
    unsigned short* wipt = (unsigned short*)(ws + 13422592);  // 4*512*128 bf16
    unsigned short* wopt = (unsigned short*)(ws + 13553664);  // 4*128*256 bf16
    float* klacc = ws + 13619200;

    hipMemsetAsync(klacc, 0, sizeof(float), stream);

    // ---- weight casts: bf16 + transpose to [N][K] ----
    castT_kernel<<<dim3(8, 128), 256, 0, stream>>>(vis_w1, w1t, 8192, 512);
    castT_kernel<<<dim3(2, 8),   256, 0, stream>>>(vis_w2, w2t, 512, 128);
    castT_kernel<<<dim3(2, 1),   256, 0, stream>>>(ego_w,  egot, 64, 128);
    castT_kernel<<<dim3(2, 4),   256, 0, stream>>>(fus_w,  fust, 256, 128);
    for (int l=0; l<LLs; l++){
        castT_kernel<<<dim3(8, 2), 256, 0, stream>>>(
            in_proj_w + (size_t)l*DD*2*II, wipt + (size_t)l*2*II*DD, DD, 2*II);
        castT_kernel<<<dim3(2, 4), 256, 0, stream>>>(
            out_proj_w + (size_t)l*II*DD, wopt + (size_t)l*DD*II, II, DD);
    }

    // 1) vision GEMM1: gelu(x_cam @ W1 + b1) -> v1g (bf16 out).
    //    fp32->bf16 conversion fused into A-staging (no cast kernel).
    gemm_f32a_kernel<1,1><<<dim3(64, 4), 512, 0, stream>>>(
        x_cam, w1t, vis_b1, v1g, MTOK, 512, 8192, 512);
    // 2) v2 = v1g @ W2 + b2 -> catbf[:, :128] (bf16 out)
    gemm_lds64_kernel<0,0,1><<<dim3(128, 2), 256, 0, stream>>>(
        v1g, w2t, vis_b2, catbf, MTOK, 128, 512, 256);
    // 3) e = x_ego @ ego_w + b -> catbf[:, 128:]  (fp32 A, K=64 -> legacy)
    gemm_bf16_kernel<0,0,1,float><<<dim3(64, 2), 256, 0, stream>>>(
        x_ego, egot, ego_b, catbf + 128, MTOK, 128, 64, 256);
    // 4) fused = gelu(catbf @ fus_w + b) -> xbuf (fp32 residual stream)
    gemm_lds64_kernel<1,0,0><<<dim3(128, 2), 256, 0, stream>>>(
        catbf, fust, fus_b, xbuf, MTOK, 128, 256, 128);

    for (int l=0; l<LLs; l++){
        rms_bf_kernel<<<MTOK/4, 256, 0, stream>>>(xbuf, norm_w + l*DD, xnbf);
        gemm_w512_kernel<0,0,0><<<dim3(64, 4), 512, 0, stream>>>(
            xnbf, wipt + (size_t)l*2*II*DD, nullptr, hg, MTOK, 2*II, DD, 2*II);
        conv_kernel<<<MTOK*II/256, 256, 0, stream>>>(
            hg, conv_w + (size_t)l*II*KKs, conv_b + (size_t)l*II, hconv);
        xproj_fused_kernel<<<MTOK/XT, 256, 0, stream>>>(
            hconv, x_proj_w + (size_t)l*II*40, dt_proj_w + (size_t)l*RRs*II,
            dt_proj_b + (size_t)l*II, dtws, bcws);
        scan_kernel<<<BQ*16, 256, 0, stream>>>(
            dtws, bcws, hconv, hg, A_log + (size_t)l*II*NNs, D_par + (size_t)l*II, ybf);
        gemm_lds64_kernel<0,1,0><<<dim3(128, 2), 256, 0, stream>>>(
            ybf, wopt + (size_t)l*DD*II, nullptr, xbuf, MTOK, DD, II, DD);
    }

    head_kernel<<<BQ, 128, 0, stream>>>(
        xbuf, normf_w, mu_w, mu_b, lv_w, lv_b, vib_eps,
        h1_w, h1_b, h2_w, h2_b, (float*)d_out, klacc);
    kl_final_kernel<<<1, 1, 0, stream>>>(klacc, (float*)d_out + 1280);
}